// Round 5
// baseline (1123.867 us; speedup 1.0000x reference)
//
#include <hip/hip_runtime.h>
#include <hip/hip_fp16.h>
#include <math.h>

#define NN 100000
#define NE 1600000
#define INF_ 128
#define HID 64
#define NEG 0.2f
#define NBLK1 98     // ceil(NN/1024) for scan
#define NPASS 8      // XCD count
#define DRNG 12500   // NN/NPASS

__device__ __forceinline__ float lrelu(float v){ return v > 0.f ? v : NEG*v; }

// ---------------- CSR build ----------------

__global__ void k_zero_i(int* p, int n){
  int i = blockIdx.x*blockDim.x + threadIdx.x;
  if (i < n) p[i] = 0;
}

__global__ void k_count(const int* __restrict__ dst, int* __restrict__ cnt){
  int e = blockIdx.x*blockDim.x + threadIdx.x;
  if (e < NE) atomicAdd(&cnt[dst[e]], 1);
}

__global__ void k_dinv(const int* __restrict__ cnt, float* __restrict__ dinv){
  int i = blockIdx.x*blockDim.x + threadIdx.x;
  if (i < NN) dinv[i] = rsqrtf((float)cnt[i] + 1.0f);
}

__global__ __launch_bounds__(256) void k_scan1(const int* __restrict__ cnt,
                                               int* __restrict__ off,
                                               int* __restrict__ part){
  __shared__ int l[256];
  int t = threadIdx.x;
  int base = blockIdx.x*1024 + t*4;
  int a0 = (base+0 < NN) ? cnt[base+0] : 0;
  int a1 = (base+1 < NN) ? cnt[base+1] : 0;
  int a2 = (base+2 < NN) ? cnt[base+2] : 0;
  int a3 = (base+3 < NN) ? cnt[base+3] : 0;
  int s = a0+a1+a2+a3;
  l[t] = s; __syncthreads();
  for (int o = 1; o < 256; o <<= 1){
    int v = (t >= o) ? l[t-o] : 0;
    __syncthreads();
    l[t] += v;
    __syncthreads();
  }
  if (t == 255) part[blockIdx.x] = l[255];
  int e0 = l[t] - s;
  if (base+0 < NN) off[base+0] = e0;
  if (base+1 < NN) off[base+1] = e0 + a0;
  if (base+2 < NN) off[base+2] = e0 + a0 + a1;
  if (base+3 < NN) off[base+3] = e0 + a0 + a1 + a2;
}

__global__ __launch_bounds__(128) void k_scan2(int* part){
  __shared__ int l[128];
  int t = threadIdx.x;
  int v = (t < NBLK1) ? part[t] : 0;
  l[t] = v; __syncthreads();
  for (int o = 1; o < 128; o <<= 1){
    int u = (t >= o) ? l[t-o] : 0;
    __syncthreads();
    l[t] += u;
    __syncthreads();
  }
  if (t < NBLK1) part[t] = l[t] - v;
}

__global__ void k_scan3(int* off, const int* __restrict__ part){
  int i = blockIdx.x*blockDim.x + threadIdx.x;
  if (i < NN) off[i] += part[i >> 10];
  if (i == 0) off[NN] = NE;
}

// XCD-affine fill: block b handles only dst-range (b&7); consecutive blocks
// round-robin across XCDs, so each dst-range's cur/off/csr lines stay in ONE
// XCD's L2 instead of bouncing through the coherence point.
__global__ __launch_bounds__(256) void k_fill8(const int* __restrict__ src,
                                               const int* __restrict__ dst,
                                               const int* __restrict__ off,
                                               int* cur, int* __restrict__ csr){
  int pass  = blockIdx.x & (NPASS-1);
  int chunk = blockIdx.x >> 3;
  int e = chunk*256 + threadIdx.x;
  if (e >= NE) return;
  int d = dst[e];
  if ((unsigned)(d - pass*DRNG) >= (unsigned)DRNG) return;
  int p = atomicAdd(&cur[d], 1);
  csr[off[d] + p] = src[e];
}

// ---------------- dense linears: 8 rows/wave, W columns in VGPRs ----------------

// hs = (x @ w) * dinv ; fp16 mirror hsH for gathers
__global__ __launch_bounds__(256) void k_gemm_in(const float* __restrict__ x,
                                                 const float* __restrict__ w,
                                                 const float* __restrict__ dinv,
                                                 float* __restrict__ hs,
                                                 __half* __restrict__ hsH){
  __shared__ float xl[4][8][INF_];
  const int wave = threadIdx.x >> 6, lane = threadIdx.x & 63;
  int rb = blockIdx.x*32 + wave*8;
  if (rb >= NN) return;
  #pragma unroll
  for (int r = 0; r < 8; ++r){
    xl[wave][r][lane]      = x[(size_t)(rb+r)*INF_ + lane];
    xl[wave][r][lane + 64] = x[(size_t)(rb+r)*INF_ + lane + 64];
  }
  float acc[8] = {0.f,0.f,0.f,0.f,0.f,0.f,0.f,0.f};
  #pragma unroll
  for (int c = 0; c < 4; ++c){
    float wv[32];
    #pragma unroll
    for (int j = 0; j < 32; ++j) wv[j] = w[(c*32 + j)*HID + lane];
    #pragma unroll
    for (int r = 0; r < 8; ++r)
      #pragma unroll
      for (int j = 0; j < 32; ++j)
        acc[r] = fmaf(xl[wave][r][c*32 + j], wv[j], acc[r]);
  }
  #pragma unroll
  for (int r = 0; r < 8; ++r){
    float v = acc[r]*dinv[rb+r];
    hs[(size_t)(rb+r)*HID + lane] = v;
    if (hsH) hsH[(size_t)(rb+r)*HID + lane] = __float2half(v);
  }
}

// h2pre = h1 @ gat_w (+fp16 mirror); as_/ad_ per-row dots
__global__ __launch_bounds__(256) void k_gat_lin(const float* __restrict__ h1,
                                                 const float* __restrict__ w,
                                                 const float* __restrict__ atts,
                                                 const float* __restrict__ attd,
                                                 float* __restrict__ h2pre,
                                                 __half* __restrict__ h2preH,
                                                 float* __restrict__ as_,
                                                 float* __restrict__ ad_){
  __shared__ float xl[4][8][HID];
  const int wave = threadIdx.x >> 6, lane = threadIdx.x & 63;
  int rb = blockIdx.x*32 + wave*8;
  if (rb >= NN) return;
  float as_l = atts[lane], ad_l = attd[lane];
  #pragma unroll
  for (int r = 0; r < 8; ++r)
    xl[wave][r][lane] = h1[(size_t)(rb+r)*HID + lane];
  float acc[8] = {0.f,0.f,0.f,0.f,0.f,0.f,0.f,0.f};
  #pragma unroll
  for (int c = 0; c < 2; ++c){
    float wv[32];
    #pragma unroll
    for (int j = 0; j < 32; ++j) wv[j] = w[(c*32 + j)*HID + lane];
    #pragma unroll
    for (int r = 0; r < 8; ++r)
      #pragma unroll
      for (int j = 0; j < 32; ++j)
        acc[r] = fmaf(xl[wave][r][c*32 + j], wv[j], acc[r]);
  }
  #pragma unroll
  for (int r = 0; r < 8; ++r){
    h2pre[(size_t)(rb+r)*HID + lane] = acc[r];
    if (h2preH) h2preH[(size_t)(rb+r)*HID + lane] = __float2half(acc[r]);
    float vs = acc[r]*as_l, vd = acc[r]*ad_l;
    #pragma unroll
    for (int o = 32; o > 0; o >>= 1){
      vs += __shfl_xor(vs, o, 64);
      vd += __shfl_xor(vd, o, 64);
    }
    if (lane == 0){ as_[rb+r] = vs; ad_[rb+r] = vd; }
  }
}

// out = mean@wl + h2@wr + b   (mean/out may alias in fallback; row-local RAW safe)
__global__ __launch_bounds__(256) void k_sage_dense(const float* mean,
                                                    const float* __restrict__ h2,
                                                    const float* __restrict__ wlh,
                                                    const float* __restrict__ wrh,
                                                    const float* __restrict__ b,
                                                    float* out){
  __shared__ float ml[4][8][HID];
  __shared__ float hl[4][8][HID];
  const int wave = threadIdx.x >> 6, lane = threadIdx.x & 63;
  int rb = blockIdx.x*32 + wave*8;
  if (rb >= NN) return;
  float bl = b[lane];
  #pragma unroll
  for (int r = 0; r < 8; ++r){
    ml[wave][r][lane] = mean[(size_t)(rb+r)*HID + lane];
    hl[wave][r][lane] = h2[(size_t)(rb+r)*HID + lane];
  }
  float acc[8] = {bl,bl,bl,bl,bl,bl,bl,bl};
  #pragma unroll
  for (int c = 0; c < 2; ++c){
    float wvl[32], wvr[32];
    #pragma unroll
    for (int j = 0; j < 32; ++j){
      wvl[j] = wlh[(c*32 + j)*HID + lane];
      wvr[j] = wrh[(c*32 + j)*HID + lane];
    }
    #pragma unroll
    for (int r = 0; r < 8; ++r)
      #pragma unroll
      for (int j = 0; j < 32; ++j){
        acc[r] = fmaf(ml[wave][r][c*32 + j], wvl[j], acc[r]);
        acc[r] = fmaf(hl[wave][r][c*32 + j], wvr[j], acc[r]);
      }
  }
  #pragma unroll
  for (int r = 0; r < 8; ++r)
    out[(size_t)(rb+r)*HID + lane] = acc[r];
}

// ---------------- gathers: 4-row-slot, 16 rows in flight; M=1 -> fp16 rows ----

// weighted row accumulate: M==1 reads 8B fp16 chunk, else 16B f32 chunk
template<int M>
__device__ __forceinline__ void row_acc(const float4* __restrict__ r4,
                                        const uint2*  __restrict__ rh,
                                        size_t s, int f, float p, float4& acc){
  if constexpr (M == 1){
    uint2 v = rh[s*16 + f];
    half2* ph = (half2*)&v;
    float2 fa = __half22float2(ph[0]);
    float2 fb = __half22float2(ph[1]);
    acc.x = fmaf(fa.x, p, acc.x); acc.y = fmaf(fa.y, p, acc.y);
    acc.z = fmaf(fb.x, p, acc.z); acc.w = fmaf(fb.y, p, acc.w);
  } else {
    float4 r = r4[s*16 + f];
    acc.x = fmaf(r.x, p, acc.x); acc.y = fmaf(r.y, p, acc.y);
    acc.z = fmaf(r.z, p, acc.z); acc.w = fmaf(r.w, p, acc.w);
  }
}

// GCN: h1 = relu((sum_s hs[s] + hs[i]) * dinv[i] + gcn_b)
template<int M>
__global__ __launch_bounds__(256) void k_gcn_gather(const int* __restrict__ csr,
                                                    const int* __restrict__ off,
                                                    const float4* __restrict__ hs4,
                                                    const uint2*  __restrict__ hsH,
                                                    const float* __restrict__ dinv,
                                                    const float4* __restrict__ gcn_b4,
                                                    float4* __restrict__ h1_4){
  int node = blockIdx.x*4 + (threadIdx.x >> 6);
  if (node >= NN) return;
  int lane = threadIdx.x & 63;
  int q = lane >> 4, f = lane & 15;
  int beg = off[node], end = off[node+1];
  float4 acc = {0.f,0.f,0.f,0.f};
  for (int c = beg; c < end; c += 64){
    int n = end - c; if (n > 64) n = 64;
    int idx = (lane < n) ? csr[c + lane] : 0;
    for (int k = 0; k < n; k += 16){
      int e0 = k + q, e1 = k + 4 + q, e2 = k + 8 + q, e3 = k + 12 + q;
      int s0 = __shfl(idx, e0, 64);
      int s1 = __shfl(idx, e1, 64);
      int s2 = __shfl(idx, e2, 64);
      int s3 = __shfl(idx, e3, 64);
      if (e0 < n) row_acc<M>(hs4, hsH, (size_t)s0, f, 1.f, acc);
      if (e1 < n) row_acc<M>(hs4, hsH, (size_t)s1, f, 1.f, acc);
      if (e2 < n) row_acc<M>(hs4, hsH, (size_t)s2, f, 1.f, acc);
      if (e3 < n) row_acc<M>(hs4, hsH, (size_t)s3, f, 1.f, acc);
    }
  }
  #pragma unroll
  for (int o = 16; o <= 32; o <<= 1){
    acc.x += __shfl_xor(acc.x, o, 64);
    acc.y += __shfl_xor(acc.y, o, 64);
    acc.z += __shfl_xor(acc.z, o, 64);
    acc.w += __shfl_xor(acc.w, o, 64);
  }
  if (q == 0){
    float4 s  = hs4[(size_t)node*16 + f];      // self term from f32
    float  di = dinv[node];
    float4 b4 = gcn_b4[f];
    float4 o;
    o.x = fmaxf((acc.x + s.x)*di + b4.x, 0.f);
    o.y = fmaxf((acc.y + s.y)*di + b4.y, 0.f);
    o.z = fmaxf((acc.z + s.z)*di + b4.z, 0.f);
    o.w = fmaxf((acc.w + s.w)*di + b4.w, 0.f);
    h1_4[(size_t)node*16 + f] = o;
  }
}

// GAT: fused segment softmax + weighted gather; writes f32 h2 (+fp16 mirror)
template<int M>
__global__ __launch_bounds__(256) void k_gat_gather(const int* __restrict__ csr,
                                                    const int* __restrict__ off,
                                                    const float* __restrict__ as_,
                                                    const float* __restrict__ ad_,
                                                    const float4* __restrict__ h2pre4,
                                                    const uint2*  __restrict__ h2preH,
                                                    const float4* __restrict__ gat_b4,
                                                    float4* __restrict__ h2_4,
                                                    uint2* __restrict__ h2H){
  int node = blockIdx.x*4 + (threadIdx.x >> 6);
  if (node >= NN) return;
  int lane = threadIdx.x & 63;
  int q = lane >> 4, f = lane & 15;
  int beg = off[node], end = off[node+1];
  float adi = ad_[node];
  float eself = lrelu(as_[node] + adi);
  float lm = -1e30f;
  for (int c = beg + lane; c < end; c += 64)
    lm = fmaxf(lm, lrelu(as_[csr[c]] + adi));
  #pragma unroll
  for (int o = 32; o > 0; o >>= 1) lm = fmaxf(lm, __shfl_xor(lm, o, 64));
  float m = fmaxf(eself, lm);
  float ps = expf(eself - m);
  float ssum = 0.f;
  float4 acc = {0.f,0.f,0.f,0.f};
  for (int c = beg; c < end; c += 64){
    int n = end - c; if (n > 64) n = 64;
    int idx = 0; float pv = 0.f;
    if (lane < n){
      idx = csr[c + lane];
      pv = expf(lrelu(as_[idx] + adi) - m);
    }
    for (int k = 0; k < n; k += 16){
      int e0 = k + q, e1 = k + 4 + q, e2 = k + 8 + q, e3 = k + 12 + q;
      int s0 = __shfl(idx, e0, 64); float p0 = __shfl(pv, e0, 64);
      int s1 = __shfl(idx, e1, 64); float p1 = __shfl(pv, e1, 64);
      int s2 = __shfl(idx, e2, 64); float p2 = __shfl(pv, e2, 64);
      int s3 = __shfl(idx, e3, 64); float p3 = __shfl(pv, e3, 64);
      if (e0 < n){ row_acc<M>(h2pre4, h2preH, (size_t)s0, f, p0, acc); ssum += p0; }
      if (e1 < n){ row_acc<M>(h2pre4, h2preH, (size_t)s1, f, p1, acc); ssum += p1; }
      if (e2 < n){ row_acc<M>(h2pre4, h2preH, (size_t)s2, f, p2, acc); ssum += p2; }
      if (e3 < n){ row_acc<M>(h2pre4, h2preH, (size_t)s3, f, p3, acc); ssum += p3; }
    }
  }
  #pragma unroll
  for (int o = 16; o <= 32; o <<= 1){
    acc.x += __shfl_xor(acc.x, o, 64);
    acc.y += __shfl_xor(acc.y, o, 64);
    acc.z += __shfl_xor(acc.z, o, 64);
    acc.w += __shfl_xor(acc.w, o, 64);
    ssum  += __shfl_xor(ssum,  o, 64);
  }
  if (q == 0){
    float inv = 1.f/(ssum + ps);
    float4 h0 = h2pre4[(size_t)node*16 + f];   // self term from f32
    float4 b4 = gat_b4[f];
    float4 o;
    o.x = fmaxf((acc.x + h0.x*ps)*inv + b4.x, 0.f);
    o.y = fmaxf((acc.y + h0.y*ps)*inv + b4.y, 0.f);
    o.z = fmaxf((acc.z + h0.z*ps)*inv + b4.z, 0.f);
    o.w = fmaxf((acc.w + h0.w*ps)*inv + b4.w, 0.f);
    h2_4[(size_t)node*16 + f] = o;
    if constexpr (M == 1){
      union { half2 h[2]; uint2 u; } pk;
      pk.h[0] = __floats2half2_rn(o.x, o.y);
      pk.h[1] = __floats2half2_rn(o.z, o.w);
      h2H[(size_t)node*16 + f] = pk.u;
    }
  }
}

// SAGE gather: mean of h2 rows
template<int M>
__global__ __launch_bounds__(256) void k_sage_gather(const int* __restrict__ csr,
                                                     const int* __restrict__ off,
                                                     const int* __restrict__ cnt,
                                                     const float4* __restrict__ h2_4,
                                                     const uint2*  __restrict__ h2H,
                                                     float4* __restrict__ mean4){
  int node = blockIdx.x*4 + (threadIdx.x >> 6);
  if (node >= NN) return;
  int lane = threadIdx.x & 63;
  int q = lane >> 4, f = lane & 15;
  int beg = off[node], end = off[node+1];
  float4 acc = {0.f,0.f,0.f,0.f};
  for (int c = beg; c < end; c += 64){
    int n = end - c; if (n > 64) n = 64;
    int idx = (lane < n) ? csr[c + lane] : 0;
    for (int k = 0; k < n; k += 16){
      int e0 = k + q, e1 = k + 4 + q, e2 = k + 8 + q, e3 = k + 12 + q;
      int s0 = __shfl(idx, e0, 64);
      int s1 = __shfl(idx, e1, 64);
      int s2 = __shfl(idx, e2, 64);
      int s3 = __shfl(idx, e3, 64);
      if (e0 < n) row_acc<M>(h2_4, h2H, (size_t)s0, f, 1.f, acc);
      if (e1 < n) row_acc<M>(h2_4, h2H, (size_t)s1, f, 1.f, acc);
      if (e2 < n) row_acc<M>(h2_4, h2H, (size_t)s2, f, 1.f, acc);
      if (e3 < n) row_acc<M>(h2_4, h2H, (size_t)s3, f, 1.f, acc);
    }
  }
  #pragma unroll
  for (int o = 16; o <= 32; o <<= 1){
    acc.x += __shfl_xor(acc.x, o, 64);
    acc.y += __shfl_xor(acc.y, o, 64);
    acc.z += __shfl_xor(acc.z, o, 64);
    acc.w += __shfl_xor(acc.w, o, 64);
  }
  if (q == 0){
    float inv = 1.f/fmaxf((float)cnt[node], 1.f);
    float4 o = {acc.x*inv, acc.y*inv, acc.z*inv, acc.w*inv};
    mean4[(size_t)node*16 + f] = o;
  }
}

// ---------------- launch ----------------

extern "C" void kernel_launch(void* const* d_in, const int* in_sizes, int n_in,
                              void* d_out, int out_size, void* d_ws, size_t ws_size,
                              hipStream_t stream) {
  const float* x      = (const float*)d_in[0];
  const int*   ei     = (const int*)d_in[1];
  const int*   src    = ei;
  const int*   dstp   = ei + NE;
  const float* gcn_w  = (const float*)d_in[2];
  const float* gcn_b  = (const float*)d_in[3];
  const float* gat_w  = (const float*)d_in[4];
  const float* att_s  = (const float*)d_in[5];
  const float* att_d  = (const float*)d_in[6];
  const float* gat_b  = (const float*)d_in[7];
  const float* s_wl   = (const float*)d_in[8];
  const float* s_wr   = (const float*)d_in[9];
  const float* s_b    = (const float*)d_in[10];
  float* outp = (float*)d_out;

  // workspace layout (4-byte words)
  int*   cnt  = (int*)d_ws;          // N
  int*   cur  = cnt + NN;            // N
  int*   off  = cur + NN;            // N+1
  int*   part = off + NN + 1;        // 1024 (pad)
  float* dinv = (float*)(part + 1024);
  float* as_  = dinv + NN;
  float* ad_  = as_  + NN;
  int*   csr  = (int*)(ad_ + NN);    // NE
  float* BIG0 = (float*)(csr + NE);  // N*HID f32
  float* BIG1 = BIG0 + (size_t)NN*HID;
  __half* HA  = (__half*)(BIG1 + (size_t)NN*HID);   // N*HID fp16
  __half* HB  = HA + (size_t)NN*HID;

  size_t base_words = (size_t)6*NN + 1 + 1024 + NE;
  size_t needB = (base_words + (size_t)2*NN*HID)*4;                 // f32 only
  size_t needA = needB + (size_t)2*NN*HID*2;                        // + 2 fp16 mirrors

  float *P_hs, *P_h1, *P_h2pre, *P_h2, *P_mean;
  __half *P_hsH = nullptr, *P_h2preH = nullptr, *P_h2H = nullptr;
  int tier;
  if (ws_size >= needA){
    tier = 1;
    P_hs = BIG0; P_h1 = BIG1; P_h2pre = outp; P_h2 = BIG1; P_mean = BIG0;
    P_hsH = HA; P_h2preH = HB; P_h2H = HA;    // hsH dead before h2H written
  } else if (ws_size >= needB){
    tier = 0;
    P_hs = BIG0; P_h1 = BIG1; P_h2pre = outp; P_h2 = BIG1; P_mean = BIG0;
  } else {
    tier = 0;
    P_hs = outp; P_h1 = BIG0; P_h2pre = outp; P_h2 = BIG0; P_mean = outp;
  }

  const int B = 256;
  const int GROWS = (NN + 31)/32;
  // CSR build
  k_zero_i<<<(2*NN + B-1)/B, B, 0, stream>>>(cnt, 2*NN);
  k_count <<<(NE + B-1)/B, B, 0, stream>>>(dstp, cnt);
  k_dinv  <<<(NN + B-1)/B, B, 0, stream>>>(cnt, dinv);
  k_scan1 <<<NBLK1, B, 0, stream>>>(cnt, off, part);
  k_scan2 <<<1, 128, 0, stream>>>(part);
  k_scan3 <<<(NN + B-1)/B, B, 0, stream>>>(off, part);
  k_fill8 <<<NPASS*((NE + B-1)/B), B, 0, stream>>>(src, dstp, off, cur, csr);

  // GCN
  k_gemm_in<<<GROWS, B, 0, stream>>>(x, gcn_w, dinv, P_hs, P_hsH);
  if (tier)
    k_gcn_gather<1><<<(NN + 3)/4, B, 0, stream>>>(csr, off, (const float4*)P_hs,
        (const uint2*)P_hsH, dinv, (const float4*)gcn_b, (float4*)P_h1);
  else
    k_gcn_gather<0><<<(NN + 3)/4, B, 0, stream>>>(csr, off, (const float4*)P_hs,
        nullptr, dinv, (const float4*)gcn_b, (float4*)P_h1);

  // GAT
  k_gat_lin<<<GROWS, B, 0, stream>>>(P_h1, gat_w, att_s, att_d, P_h2pre, P_h2preH, as_, ad_);
  if (tier)
    k_gat_gather<1><<<(NN + 3)/4, B, 0, stream>>>(csr, off, as_, ad_,
        (const float4*)P_h2pre, (const uint2*)P_h2preH, (const float4*)gat_b,
        (float4*)P_h2, (uint2*)P_h2H);
  else
    k_gat_gather<0><<<(NN + 3)/4, B, 0, stream>>>(csr, off, as_, ad_,
        (const float4*)P_h2pre, nullptr, (const float4*)gat_b,
        (float4*)P_h2, nullptr);

  // SAGE
  if (tier)
    k_sage_gather<1><<<(NN + 3)/4, B, 0, stream>>>(csr, off, cnt,
        (const float4*)P_h2, (const uint2*)P_h2H, (float4*)P_mean);
  else
    k_sage_gather<0><<<(NN + 3)/4, B, 0, stream>>>(csr, off, cnt,
        (const float4*)P_h2, nullptr, (float4*)P_mean);
  k_sage_dense<<<GROWS, B, 0, stream>>>(P_mean, P_h2, s_wl, s_wr, s_b, outp);
}

// Round 6
// 486.887 us; speedup vs baseline: 2.3083x; 2.3083x over previous
//
#include <hip/hip_runtime.h>
#include <hip/hip_fp16.h>
#include <math.h>

#define NN 100000
#define NE 1600000
#define INF_ 128
#define HID 64
#define NEG 0.2f
#define NBLK1 98     // ceil(NN/1024) for scan
#define NPASS 8      // XCD count
#define DRNG 12500   // NN/NPASS

__device__ __forceinline__ float lrelu(float v){ return v > 0.f ? v : NEG*v; }

// ---------------- CSR build ----------------

__global__ void k_zero_i(int* p, int n){
  int i = blockIdx.x*blockDim.x + threadIdx.x;
  if (i < n) p[i] = 0;
}

__global__ void k_count(const int* __restrict__ dst, int* __restrict__ cnt){
  int e = blockIdx.x*blockDim.x + threadIdx.x;
  if (e < NE) atomicAdd(&cnt[dst[e]], 1);
}

__global__ void k_dinv(const int* __restrict__ cnt, float* __restrict__ dinv){
  int i = blockIdx.x*blockDim.x + threadIdx.x;
  if (i < NN) dinv[i] = rsqrtf((float)cnt[i] + 1.0f);
}

__global__ __launch_bounds__(256) void k_scan1(const int* __restrict__ cnt,
                                               int* __restrict__ off,
                                               int* __restrict__ part){
  __shared__ int l[256];
  int t = threadIdx.x;
  int base = blockIdx.x*1024 + t*4;
  int a0 = (base+0 < NN) ? cnt[base+0] : 0;
  int a1 = (base+1 < NN) ? cnt[base+1] : 0;
  int a2 = (base+2 < NN) ? cnt[base+2] : 0;
  int a3 = (base+3 < NN) ? cnt[base+3] : 0;
  int s = a0+a1+a2+a3;
  l[t] = s; __syncthreads();
  for (int o = 1; o < 256; o <<= 1){
    int v = (t >= o) ? l[t-o] : 0;
    __syncthreads();
    l[t] += v;
    __syncthreads();
  }
  if (t == 255) part[blockIdx.x] = l[255];
  int e0 = l[t] - s;
  if (base+0 < NN) off[base+0] = e0;
  if (base+1 < NN) off[base+1] = e0 + a0;
  if (base+2 < NN) off[base+2] = e0 + a0 + a1;
  if (base+3 < NN) off[base+3] = e0 + a0 + a1 + a2;
}

__global__ __launch_bounds__(128) void k_scan2(int* part){
  __shared__ int l[128];
  int t = threadIdx.x;
  int v = (t < NBLK1) ? part[t] : 0;
  l[t] = v; __syncthreads();
  for (int o = 1; o < 128; o <<= 1){
    int u = (t >= o) ? l[t-o] : 0;
    __syncthreads();
    l[t] += u;
    __syncthreads();
  }
  if (t < NBLK1) part[t] = l[t] - v;
}

__global__ void k_scan3(int* off, const int* __restrict__ part){
  int i = blockIdx.x*blockDim.x + threadIdx.x;
  if (i < NN) off[i] += part[i >> 10];
  if (i == 0) off[NN] = NE;
}

// XCD-affine fill: block b handles only dst-range (b&7)
__global__ __launch_bounds__(256) void k_fill8(const int* __restrict__ src,
                                               const int* __restrict__ dst,
                                               const int* __restrict__ off,
                                               int* cur, int* __restrict__ csr){
  int pass  = blockIdx.x & (NPASS-1);
  int chunk = blockIdx.x >> 3;
  int e = chunk*256 + threadIdx.x;
  if (e >= NE) return;
  int d = dst[e];
  if ((unsigned)(d - pass*DRNG) >= (unsigned)DRNG) return;
  int p = atomicAdd(&cur[d], 1);
  csr[off[d] + p] = src[e];
}

// fp16 cast: 4 elems/thread, pure streaming
__global__ void k_cast_h(const float4* __restrict__ s, uint2* __restrict__ d, int n4){
  int i = blockIdx.x*blockDim.x + threadIdx.x;
  if (i < n4){
    float4 v = s[i];
    union { half2 h[2]; uint2 u; } pk;
    pk.h[0] = __floats2half2_rn(v.x, v.y);
    pk.h[1] = __floats2half2_rn(v.z, v.w);
    d[i] = pk.u;
  }
}

// ---------------- dense linears (round-4 versions, no mirrors) ----------------

// hs = (x @ w) * dinv
__global__ __launch_bounds__(256) void k_gemm_in(const float* __restrict__ x,
                                                 const float* __restrict__ w,
                                                 const float* __restrict__ dinv,
                                                 float* __restrict__ hs){
  __shared__ float xl[4][8][INF_];
  const int wave = threadIdx.x >> 6, lane = threadIdx.x & 63;
  int rb = blockIdx.x*32 + wave*8;
  if (rb >= NN) return;
  #pragma unroll
  for (int r = 0; r < 8; ++r){
    xl[wave][r][lane]      = x[(size_t)(rb+r)*INF_ + lane];
    xl[wave][r][lane + 64] = x[(size_t)(rb+r)*INF_ + lane + 64];
  }
  float acc[8] = {0.f,0.f,0.f,0.f,0.f,0.f,0.f,0.f};
  #pragma unroll
  for (int c = 0; c < 4; ++c){
    float wv[32];
    #pragma unroll
    for (int j = 0; j < 32; ++j) wv[j] = w[(c*32 + j)*HID + lane];
    #pragma unroll
    for (int r = 0; r < 8; ++r)
      #pragma unroll
      for (int j = 0; j < 32; ++j)
        acc[r] = fmaf(xl[wave][r][c*32 + j], wv[j], acc[r]);
  }
  #pragma unroll
  for (int r = 0; r < 8; ++r)
    hs[(size_t)(rb+r)*HID + lane] = acc[r]*dinv[rb+r];
}

// h2pre = h1 @ gat_w; as_/ad_ per-row dots
__global__ __launch_bounds__(256) void k_gat_lin(const float* __restrict__ h1,
                                                 const float* __restrict__ w,
                                                 const float* __restrict__ atts,
                                                 const float* __restrict__ attd,
                                                 float* __restrict__ h2pre,
                                                 float* __restrict__ as_,
                                                 float* __restrict__ ad_){
  __shared__ float xl[4][8][HID];
  const int wave = threadIdx.x >> 6, lane = threadIdx.x & 63;
  int rb = blockIdx.x*32 + wave*8;
  if (rb >= NN) return;
  float as_l = atts[lane], ad_l = attd[lane];
  #pragma unroll
  for (int r = 0; r < 8; ++r)
    xl[wave][r][lane] = h1[(size_t)(rb+r)*HID + lane];
  float acc[8] = {0.f,0.f,0.f,0.f,0.f,0.f,0.f,0.f};
  #pragma unroll
  for (int c = 0; c < 2; ++c){
    float wv[32];
    #pragma unroll
    for (int j = 0; j < 32; ++j) wv[j] = w[(c*32 + j)*HID + lane];
    #pragma unroll
    for (int r = 0; r < 8; ++r)
      #pragma unroll
      for (int j = 0; j < 32; ++j)
        acc[r] = fmaf(xl[wave][r][c*32 + j], wv[j], acc[r]);
  }
  #pragma unroll
  for (int r = 0; r < 8; ++r){
    h2pre[(size_t)(rb+r)*HID + lane] = acc[r];
    float vs = acc[r]*as_l, vd = acc[r]*ad_l;
    #pragma unroll
    for (int o = 32; o > 0; o >>= 1){
      vs += __shfl_xor(vs, o, 64);
      vd += __shfl_xor(vd, o, 64);
    }
    if (lane == 0){ as_[rb+r] = vs; ad_[rb+r] = vd; }
  }
}

// out = mean@wl + h2@wr + b   (mean/out may alias in fallback; row-local RAW safe)
__global__ __launch_bounds__(256) void k_sage_dense(const float* mean,
                                                    const float* __restrict__ h2,
                                                    const float* __restrict__ wlh,
                                                    const float* __restrict__ wrh,
                                                    const float* __restrict__ b,
                                                    float* out){
  __shared__ float ml[4][8][HID];
  __shared__ float hl[4][8][HID];
  const int wave = threadIdx.x >> 6, lane = threadIdx.x & 63;
  int rb = blockIdx.x*32 + wave*8;
  if (rb >= NN) return;
  float bl = b[lane];
  #pragma unroll
  for (int r = 0; r < 8; ++r){
    ml[wave][r][lane] = mean[(size_t)(rb+r)*HID + lane];
    hl[wave][r][lane] = h2[(size_t)(rb+r)*HID + lane];
  }
  float acc[8] = {bl,bl,bl,bl,bl,bl,bl,bl};
  #pragma unroll
  for (int c = 0; c < 2; ++c){
    float wvl[32], wvr[32];
    #pragma unroll
    for (int j = 0; j < 32; ++j){
      wvl[j] = wlh[(c*32 + j)*HID + lane];
      wvr[j] = wrh[(c*32 + j)*HID + lane];
    }
    #pragma unroll
    for (int r = 0; r < 8; ++r)
      #pragma unroll
      for (int j = 0; j < 32; ++j){
        acc[r] = fmaf(ml[wave][r][c*32 + j], wvl[j], acc[r]);
        acc[r] = fmaf(hl[wave][r][c*32 + j], wvr[j], acc[r]);
      }
  }
  #pragma unroll
  for (int r = 0; r < 8; ++r)
    out[(size_t)(rb+r)*HID + lane] = acc[r];
}

// ---------------- gathers: 4-row-slot, 16 rows in flight; M=1 -> fp16 rows ----

template<int M>
__device__ __forceinline__ void row_acc(const float4* __restrict__ r4,
                                        const uint2*  __restrict__ rh,
                                        size_t s, int f, float p, float4& acc){
  if constexpr (M == 1){
    uint2 v = rh[s*16 + f];
    half2* ph = (half2*)&v;
    float2 fa = __half22float2(ph[0]);
    float2 fb = __half22float2(ph[1]);
    acc.x = fmaf(fa.x, p, acc.x); acc.y = fmaf(fa.y, p, acc.y);
    acc.z = fmaf(fb.x, p, acc.z); acc.w = fmaf(fb.y, p, acc.w);
  } else {
    float4 r = r4[s*16 + f];
    acc.x = fmaf(r.x, p, acc.x); acc.y = fmaf(r.y, p, acc.y);
    acc.z = fmaf(r.z, p, acc.z); acc.w = fmaf(r.w, p, acc.w);
  }
}

// GCN: h1 = relu((sum_s hs[s] + hs[i]) * dinv[i] + gcn_b)
template<int M>
__global__ __launch_bounds__(256) void k_gcn_gather(const int* __restrict__ csr,
                                                    const int* __restrict__ off,
                                                    const float4* __restrict__ hs4,
                                                    const uint2*  __restrict__ hsH,
                                                    const float* __restrict__ dinv,
                                                    const float4* __restrict__ gcn_b4,
                                                    float4* __restrict__ h1_4){
  int node = blockIdx.x*4 + (threadIdx.x >> 6);
  if (node >= NN) return;
  int lane = threadIdx.x & 63;
  int q = lane >> 4, f = lane & 15;
  int beg = off[node], end = off[node+1];
  float4 acc = {0.f,0.f,0.f,0.f};
  for (int c = beg; c < end; c += 64){
    int n = end - c; if (n > 64) n = 64;
    int idx = (lane < n) ? csr[c + lane] : 0;
    for (int k = 0; k < n; k += 16){
      int e0 = k + q, e1 = k + 4 + q, e2 = k + 8 + q, e3 = k + 12 + q;
      int s0 = __shfl(idx, e0, 64);
      int s1 = __shfl(idx, e1, 64);
      int s2 = __shfl(idx, e2, 64);
      int s3 = __shfl(idx, e3, 64);
      if (e0 < n) row_acc<M>(hs4, hsH, (size_t)s0, f, 1.f, acc);
      if (e1 < n) row_acc<M>(hs4, hsH, (size_t)s1, f, 1.f, acc);
      if (e2 < n) row_acc<M>(hs4, hsH, (size_t)s2, f, 1.f, acc);
      if (e3 < n) row_acc<M>(hs4, hsH, (size_t)s3, f, 1.f, acc);
    }
  }
  #pragma unroll
  for (int o = 16; o <= 32; o <<= 1){
    acc.x += __shfl_xor(acc.x, o, 64);
    acc.y += __shfl_xor(acc.y, o, 64);
    acc.z += __shfl_xor(acc.z, o, 64);
    acc.w += __shfl_xor(acc.w, o, 64);
  }
  if (q == 0){
    float4 s  = hs4[(size_t)node*16 + f];      // self term from f32
    float  di = dinv[node];
    float4 b4 = gcn_b4[f];
    float4 o;
    o.x = fmaxf((acc.x + s.x)*di + b4.x, 0.f);
    o.y = fmaxf((acc.y + s.y)*di + b4.y, 0.f);
    o.z = fmaxf((acc.z + s.z)*di + b4.z, 0.f);
    o.w = fmaxf((acc.w + s.w)*di + b4.w, 0.f);
    h1_4[(size_t)node*16 + f] = o;
  }
}

// GAT: fused segment softmax + weighted gather
template<int M>
__global__ __launch_bounds__(256) void k_gat_gather(const int* __restrict__ csr,
                                                    const int* __restrict__ off,
                                                    const float* __restrict__ as_,
                                                    const float* __restrict__ ad_,
                                                    const float4* __restrict__ h2pre4,
                                                    const uint2*  __restrict__ h2preH,
                                                    const float4* __restrict__ gat_b4,
                                                    float4* __restrict__ h2_4){
  int node = blockIdx.x*4 + (threadIdx.x >> 6);
  if (node >= NN) return;
  int lane = threadIdx.x & 63;
  int q = lane >> 4, f = lane & 15;
  int beg = off[node], end = off[node+1];
  float adi = ad_[node];
  float eself = lrelu(as_[node] + adi);
  float lm = -1e30f;
  for (int c = beg + lane; c < end; c += 64)
    lm = fmaxf(lm, lrelu(as_[csr[c]] + adi));
  #pragma unroll
  for (int o = 32; o > 0; o >>= 1) lm = fmaxf(lm, __shfl_xor(lm, o, 64));
  float m = fmaxf(eself, lm);
  float ps = expf(eself - m);
  float ssum = 0.f;
  float4 acc = {0.f,0.f,0.f,0.f};
  for (int c = beg; c < end; c += 64){
    int n = end - c; if (n > 64) n = 64;
    int idx = 0; float pv = 0.f;
    if (lane < n){
      idx = csr[c + lane];
      pv = expf(lrelu(as_[idx] + adi) - m);
    }
    for (int k = 0; k < n; k += 16){
      int e0 = k + q, e1 = k + 4 + q, e2 = k + 8 + q, e3 = k + 12 + q;
      int s0 = __shfl(idx, e0, 64); float p0 = __shfl(pv, e0, 64);
      int s1 = __shfl(idx, e1, 64); float p1 = __shfl(pv, e1, 64);
      int s2 = __shfl(idx, e2, 64); float p2 = __shfl(pv, e2, 64);
      int s3 = __shfl(idx, e3, 64); float p3 = __shfl(pv, e3, 64);
      if (e0 < n){ row_acc<M>(h2pre4, h2preH, (size_t)s0, f, p0, acc); ssum += p0; }
      if (e1 < n){ row_acc<M>(h2pre4, h2preH, (size_t)s1, f, p1, acc); ssum += p1; }
      if (e2 < n){ row_acc<M>(h2pre4, h2preH, (size_t)s2, f, p2, acc); ssum += p2; }
      if (e3 < n){ row_acc<M>(h2pre4, h2preH, (size_t)s3, f, p3, acc); ssum += p3; }
    }
  }
  #pragma unroll
  for (int o = 16; o <= 32; o <<= 1){
    acc.x += __shfl_xor(acc.x, o, 64);
    acc.y += __shfl_xor(acc.y, o, 64);
    acc.z += __shfl_xor(acc.z, o, 64);
    acc.w += __shfl_xor(acc.w, o, 64);
    ssum  += __shfl_xor(ssum,  o, 64);
  }
  if (q == 0){
    float inv = 1.f/(ssum + ps);
    float4 h0 = h2pre4[(size_t)node*16 + f];   // self term from f32
    float4 b4 = gat_b4[f];
    float4 o;
    o.x = fmaxf((acc.x + h0.x*ps)*inv + b4.x, 0.f);
    o.y = fmaxf((acc.y + h0.y*ps)*inv + b4.y, 0.f);
    o.z = fmaxf((acc.z + h0.z*ps)*inv + b4.z, 0.f);
    o.w = fmaxf((acc.w + h0.w*ps)*inv + b4.w, 0.f);
    h2_4[(size_t)node*16 + f] = o;
  }
}

// SAGE gather: mean of h2 rows
template<int M>
__global__ __launch_bounds__(256) void k_sage_gather(const int* __restrict__ csr,
                                                     const int* __restrict__ off,
                                                     const int* __restrict__ cnt,
                                                     const float4* __restrict__ h2_4,
                                                     const uint2*  __restrict__ h2H,
                                                     float4* __restrict__ mean4){
  int node = blockIdx.x*4 + (threadIdx.x >> 6);
  if (node >= NN) return;
  int lane = threadIdx.x & 63;
  int q = lane >> 4, f = lane & 15;
  int beg = off[node], end = off[node+1];
  float4 acc = {0.f,0.f,0.f,0.f};
  for (int c = beg; c < end; c += 64){
    int n = end - c; if (n > 64) n = 64;
    int idx = (lane < n) ? csr[c + lane] : 0;
    for (int k = 0; k < n; k += 16){
      int e0 = k + q, e1 = k + 4 + q, e2 = k + 8 + q, e3 = k + 12 + q;
      int s0 = __shfl(idx, e0, 64);
      int s1 = __shfl(idx, e1, 64);
      int s2 = __shfl(idx, e2, 64);
      int s3 = __shfl(idx, e3, 64);
      if (e0 < n) row_acc<M>(h2_4, h2H, (size_t)s0, f, 1.f, acc);
      if (e1 < n) row_acc<M>(h2_4, h2H, (size_t)s1, f, 1.f, acc);
      if (e2 < n) row_acc<M>(h2_4, h2H, (size_t)s2, f, 1.f, acc);
      if (e3 < n) row_acc<M>(h2_4, h2H, (size_t)s3, f, 1.f, acc);
    }
  }
  #pragma unroll
  for (int o = 16; o <= 32; o <<= 1){
    acc.x += __shfl_xor(acc.x, o, 64);
    acc.y += __shfl_xor(acc.y, o, 64);
    acc.z += __shfl_xor(acc.z, o, 64);
    acc.w += __shfl_xor(acc.w, o, 64);
  }
  if (q == 0){
    float inv = 1.f/fmaxf((float)cnt[node], 1.f);
    float4 o = {acc.x*inv, acc.y*inv, acc.z*inv, acc.w*inv};
    mean4[(size_t)node*16 + f] = o;
  }
}

// ---------------- launch ----------------

extern "C" void kernel_launch(void* const* d_in, const int* in_sizes, int n_in,
                              void* d_out, int out_size, void* d_ws, size_t ws_size,
                              hipStream_t stream) {
  const float* x      = (const float*)d_in[0];
  const int*   ei     = (const int*)d_in[1];
  const int*   src    = ei;
  const int*   dstp   = ei + NE;
  const float* gcn_w  = (const float*)d_in[2];
  const float* gcn_b  = (const float*)d_in[3];
  const float* gat_w  = (const float*)d_in[4];
  const float* att_s  = (const float*)d_in[5];
  const float* att_d  = (const float*)d_in[6];
  const float* gat_b  = (const float*)d_in[7];
  const float* s_wl   = (const float*)d_in[8];
  const float* s_wr   = (const float*)d_in[9];
  const float* s_b    = (const float*)d_in[10];
  float* outp = (float*)d_out;

  // workspace layout (4-byte words)
  int*   cnt  = (int*)d_ws;          // N
  int*   cur  = cnt + NN;            // N
  int*   off  = cur + NN;            // N+1
  int*   part = off + NN + 1;        // 1024 (pad)
  float* dinv = (float*)(part + 1024);
  float* as_  = dinv + NN;
  float* ad_  = as_  + NN;
  int*   csr  = (int*)(ad_ + NN);    // NE
  float* BIG0 = (float*)(csr + NE);  // N*HID f32
  float* BIG1 = BIG0 + (size_t)NN*HID;

  size_t base_words = (size_t)6*NN + 1 + 1024 + NE;
  size_t need2 = (base_words + (size_t)2*NN*HID)*4;   // 2 big f32 ws buffers

  const size_t NH = (size_t)NN*HID;
  const int B = 256;
  const int GROWS = (NN + 31)/32;
  const int GG = (NN + 3)/4;
  const int NC4 = (int)(NH/4);

  // CSR build
  k_zero_i<<<(2*NN + B-1)/B, B, 0, stream>>>(cnt, 2*NN);
  k_count <<<(NE + B-1)/B, B, 0, stream>>>(dstp, cnt);
  k_dinv  <<<(NN + B-1)/B, B, 0, stream>>>(cnt, dinv);
  k_scan1 <<<NBLK1, B, 0, stream>>>(cnt, off, part);
  k_scan2 <<<1, 128, 0, stream>>>(part);
  k_scan3 <<<(NN + B-1)/B, B, 0, stream>>>(off, part);
  k_fill8 <<<NPASS*((NE + B-1)/B), B, 0, stream>>>(src, dstp, off, cur, csr);

  if (ws_size >= need2){
    // fp16 tier: f32 ping-pong in ws; fp16 mirrors live in d_out (free until the
    // final k_sage_dense write). hsH dies after gcn_gather -> h2H reuses its slot.
    float* P_hs    = BIG0;
    float* P_h1    = BIG1;
    float* P_h2pre = BIG0;                 // hs dead after gcn_gather
    float* P_h2    = BIG1;                 // h1 dead after gat_lin
    float* P_mean  = BIG0;                 // h2pre dead after gat_gather
    __half* HS_H    = (__half*)outp;       // NH halfs (first half of d_out)
    __half* H2PRE_H = (__half*)outp + NH;  // NH halfs (second half)
    __half* H2_H    = (__half*)outp;       // reuse hsH slot

    // GCN
    k_gemm_in<<<GROWS, B, 0, stream>>>(x, gcn_w, dinv, P_hs);
    k_cast_h <<<(NC4 + B-1)/B, B, 0, stream>>>((const float4*)P_hs, (uint2*)HS_H, NC4);
    k_gcn_gather<1><<<GG, B, 0, stream>>>(csr, off, (const float4*)P_hs,
        (const uint2*)HS_H, dinv, (const float4*)gcn_b, (float4*)P_h1);

    // GAT
    k_gat_lin<<<GROWS, B, 0, stream>>>(P_h1, gat_w, att_s, att_d, P_h2pre, as_, ad_);
    k_cast_h <<<(NC4 + B-1)/B, B, 0, stream>>>((const float4*)P_h2pre, (uint2*)H2PRE_H, NC4);
    k_gat_gather<1><<<GG, B, 0, stream>>>(csr, off, as_, ad_,
        (const float4*)P_h2pre, (const uint2*)H2PRE_H, (const float4*)gat_b,
        (float4*)P_h2);

    // SAGE
    k_cast_h <<<(NC4 + B-1)/B, B, 0, stream>>>((const float4*)P_h2, (uint2*)H2_H, NC4);
    k_sage_gather<1><<<GG, B, 0, stream>>>(csr, off, cnt,
        (const float4*)P_h2, (const uint2*)H2_H, (float4*)P_mean);
    k_sage_dense<<<GROWS, B, 0, stream>>>(P_mean, P_h2, s_wl, s_wr, s_b, outp);
  } else {
    // f32 fallback: d_out time-shared as a big buffer (round-4 layout)
    float* P_hs    = outp;
    float* P_h1    = BIG0;
    float* P_h2pre = outp;
    float* P_h2    = BIG0;
    float* P_mean  = outp;

    k_gemm_in<<<GROWS, B, 0, stream>>>(x, gcn_w, dinv, P_hs);
    k_gcn_gather<0><<<GG, B, 0, stream>>>(csr, off, (const float4*)P_hs,
        nullptr, dinv, (const float4*)gcn_b, (float4*)P_h1);
    k_gat_lin<<<GROWS, B, 0, stream>>>(P_h1, gat_w, att_s, att_d, P_h2pre, as_, ad_);
    k_gat_gather<0><<<GG, B, 0, stream>>>(csr, off, as_, ad_,
        (const float4*)P_h2pre, nullptr, (const float4*)gat_b, (float4*)P_h2);
    k_sage_gather<0><<<GG, B, 0, stream>>>(csr, off, cnt,
        (const float4*)P_h2, nullptr, (float4*)P_mean);
    k_sage_dense<<<GROWS, B, 0, stream>>>(P_mean, P_h2, s_wl, s_wr, s_b, outp);
  }
}

// Round 7
// 415.109 us; speedup vs baseline: 2.7074x; 1.1729x over previous
//
#include <hip/hip_runtime.h>
#include <hip/hip_fp16.h>
#include <math.h>

#define NN 100000
#define NE 1600000
#define INF_ 128
#define HID 64
#define NEG 0.2f
#define NBLK1 98     // ceil(NN/1024) for scan
#define NPASS 8      // XCD count
#define DRNG 12500   // NN/NPASS

__device__ __forceinline__ float lrelu(float v){ return v > 0.f ? v : NEG*v; }

// ---------------- CSR build ----------------

__global__ void k_zero_i(int* p, int n){
  int i = blockIdx.x*blockDim.x + threadIdx.x;
  if (i < n) p[i] = 0;
}

__global__ void k_count(const int* __restrict__ dst, int* __restrict__ cnt){
  int e = blockIdx.x*blockDim.x + threadIdx.x;
  if (e < NE) atomicAdd(&cnt[dst[e]], 1);
}

__global__ void k_dinv(const int* __restrict__ cnt, float* __restrict__ dinv){
  int i = blockIdx.x*blockDim.x + threadIdx.x;
  if (i < NN) dinv[i] = rsqrtf((float)cnt[i] + 1.0f);
}

__global__ __launch_bounds__(256) void k_scan1(const int* __restrict__ cnt,
                                               int* __restrict__ off,
                                               int* __restrict__ part){
  __shared__ int l[256];
  int t = threadIdx.x;
  int base = blockIdx.x*1024 + t*4;
  int a0 = (base+0 < NN) ? cnt[base+0] : 0;
  int a1 = (base+1 < NN) ? cnt[base+1] : 0;
  int a2 = (base+2 < NN) ? cnt[base+2] : 0;
  int a3 = (base+3 < NN) ? cnt[base+3] : 0;
  int s = a0+a1+a2+a3;
  l[t] = s; __syncthreads();
  for (int o = 1; o < 256; o <<= 1){
    int v = (t >= o) ? l[t-o] : 0;
    __syncthreads();
    l[t] += v;
    __syncthreads();
  }
  if (t == 255) part[blockIdx.x] = l[255];
  int e0 = l[t] - s;
  if (base+0 < NN) off[base+0] = e0;
  if (base+1 < NN) off[base+1] = e0 + a0;
  if (base+2 < NN) off[base+2] = e0 + a0 + a1;
  if (base+3 < NN) off[base+3] = e0 + a0 + a1 + a2;
}

__global__ __launch_bounds__(128) void k_scan2(int* part){
  __shared__ int l[128];
  int t = threadIdx.x;
  int v = (t < NBLK1) ? part[t] : 0;
  l[t] = v; __syncthreads();
  for (int o = 1; o < 128; o <<= 1){
    int u = (t >= o) ? l[t-o] : 0;
    __syncthreads();
    l[t] += u;
    __syncthreads();
  }
  if (t < NBLK1) part[t] = l[t] - v;
}

__global__ void k_scan3(int* off, const int* __restrict__ part){
  int i = blockIdx.x*blockDim.x + threadIdx.x;
  if (i < NN) off[i] += part[i >> 10];
  if (i == 0) off[NN] = NE;
}

// XCD-affine fill: block b handles only dst-range (b&7)
__global__ __launch_bounds__(256) void k_fill8(const int* __restrict__ src,
                                               const int* __restrict__ dst,
                                               const int* __restrict__ off,
                                               int* cur, int* __restrict__ csr){
  int pass  = blockIdx.x & (NPASS-1);
  int chunk = blockIdx.x >> 3;
  int e = chunk*256 + threadIdx.x;
  if (e >= NE) return;
  int d = dst[e];
  if ((unsigned)(d - pass*DRNG) >= (unsigned)DRNG) return;
  int p = atomicAdd(&cur[d], 1);
  csr[off[d] + p] = src[e];
}

// fp16 cast: 4 elems/thread, pure streaming
__global__ void k_cast_h(const float4* __restrict__ s, uint2* __restrict__ d, int n4){
  int i = blockIdx.x*blockDim.x + threadIdx.x;
  if (i < n4){
    float4 v = s[i];
    union { half2 h[2]; uint2 u; } pk;
    pk.h[0] = __floats2half2_rn(v.x, v.y);
    pk.h[1] = __floats2half2_rn(v.z, v.w);
    d[i] = pk.u;
  }
}

// ---------------- dense linears: 8 rows/wave, 16-reg weight chunks ----------------

// hs = (x @ w) * dinv
__global__ __launch_bounds__(256) void k_gemm_in(const float* __restrict__ x,
                                                 const float* __restrict__ w,
                                                 const float* __restrict__ dinv,
                                                 float* __restrict__ hs){
  __shared__ float xl[4][8][INF_];
  const int wave = threadIdx.x >> 6, lane = threadIdx.x & 63;
  int rb = blockIdx.x*32 + wave*8;
  if (rb >= NN) return;
  #pragma unroll
  for (int r = 0; r < 8; ++r){
    xl[wave][r][lane]      = x[(size_t)(rb+r)*INF_ + lane];
    xl[wave][r][lane + 64] = x[(size_t)(rb+r)*INF_ + lane + 64];
  }
  float acc[8] = {0.f,0.f,0.f,0.f,0.f,0.f,0.f,0.f};
  #pragma unroll
  for (int c = 0; c < 8; ++c){
    float wv[16];
    #pragma unroll
    for (int j = 0; j < 16; ++j) wv[j] = w[(c*16 + j)*HID + lane];
    #pragma unroll
    for (int r = 0; r < 8; ++r)
      #pragma unroll
      for (int j = 0; j < 16; ++j)
        acc[r] = fmaf(xl[wave][r][c*16 + j], wv[j], acc[r]);
  }
  #pragma unroll
  for (int r = 0; r < 8; ++r)
    hs[(size_t)(rb+r)*HID + lane] = acc[r]*dinv[rb+r];
}

// h2pre = h1 @ gat_w; as_/ad_ via LDS-transpose dot (low reg pressure)
__global__ __launch_bounds__(256, 4) void k_gat_lin(const float* __restrict__ h1,
                                                    const float* __restrict__ w,
                                                    const float* __restrict__ atts,
                                                    const float* __restrict__ attd,
                                                    float* __restrict__ h2pre,
                                                    float* __restrict__ as_,
                                                    float* __restrict__ ad_){
  __shared__ float xl[4][8][HID];
  __shared__ float asl[HID], adl[HID];
  if (threadIdx.x < HID){
    asl[threadIdx.x] = atts[threadIdx.x];
    adl[threadIdx.x] = attd[threadIdx.x];
  }
  __syncthreads();
  const int wave = threadIdx.x >> 6, lane = threadIdx.x & 63;
  int rb = blockIdx.x*32 + wave*8;
  if (rb >= NN) return;
  #pragma unroll
  for (int r = 0; r < 8; ++r)
    xl[wave][r][lane] = h1[(size_t)(rb+r)*HID + lane];
  float acc[8] = {0.f,0.f,0.f,0.f,0.f,0.f,0.f,0.f};
  #pragma unroll
  for (int c = 0; c < 4; ++c){
    float wv[16];
    #pragma unroll
    for (int j = 0; j < 16; ++j) wv[j] = w[(c*16 + j)*HID + lane];
    #pragma unroll
    for (int r = 0; r < 8; ++r)
      #pragma unroll
      for (int j = 0; j < 16; ++j)
        acc[r] = fmaf(xl[wave][r][c*16 + j], wv[j], acc[r]);
  }
  #pragma unroll
  for (int r = 0; r < 8; ++r){
    h2pre[(size_t)(rb+r)*HID + lane] = acc[r];
    xl[wave][r][lane] = acc[r];          // wave-private; staging already consumed
  }
  // dots: 8 lanes per row, 8 features per lane, 3-stage reduce
  int rr = lane >> 3, t = lane & 7;
  float vs = 0.f, vd = 0.f;
  #pragma unroll
  for (int i = 0; i < 8; ++i){
    float v = xl[wave][rr][t + 8*i];
    vs = fmaf(v, asl[t + 8*i], vs);
    vd = fmaf(v, adl[t + 8*i], vd);
  }
  #pragma unroll
  for (int o = 1; o < 8; o <<= 1){
    vs += __shfl_xor(vs, o, 64);
    vd += __shfl_xor(vd, o, 64);
  }
  if (t == 0){ as_[rb + rr] = vs; ad_[rb + rr] = vd; }
}

// out = mean@wl + h2@wr + b   (mean/out may alias in fallback; row-local RAW safe)
__global__ __launch_bounds__(256, 4) void k_sage_dense(const float* mean,
                                                       const float* __restrict__ h2,
                                                       const float* __restrict__ wlh,
                                                       const float* __restrict__ wrh,
                                                       const float* __restrict__ b,
                                                       float* out){
  __shared__ float ml[4][8][HID];
  __shared__ float hl[4][8][HID];
  const int wave = threadIdx.x >> 6, lane = threadIdx.x & 63;
  int rb = blockIdx.x*32 + wave*8;
  if (rb >= NN) return;
  float bl = b[lane];
  #pragma unroll
  for (int r = 0; r < 8; ++r){
    ml[wave][r][lane] = mean[(size_t)(rb+r)*HID + lane];
    hl[wave][r][lane] = h2[(size_t)(rb+r)*HID + lane];
  }
  float acc[8] = {bl,bl,bl,bl,bl,bl,bl,bl};
  #pragma unroll
  for (int c = 0; c < 4; ++c){
    float wvl[16], wvr[16];
    #pragma unroll
    for (int j = 0; j < 16; ++j){
      wvl[j] = wlh[(c*16 + j)*HID + lane];
      wvr[j] = wrh[(c*16 + j)*HID + lane];
    }
    #pragma unroll
    for (int r = 0; r < 8; ++r)
      #pragma unroll
      for (int j = 0; j < 16; ++j){
        acc[r] = fmaf(ml[wave][r][c*16 + j], wvl[j], acc[r]);
        acc[r] = fmaf(hl[wave][r][c*16 + j], wvr[j], acc[r]);
      }
  }
  #pragma unroll
  for (int r = 0; r < 8; ++r)
    out[(size_t)(rb+r)*HID + lane] = acc[r];
}

// ---------------- gathers: 4-row-slot, 16 rows in flight; M=1 -> fp16 rows ----

template<int M>
__device__ __forceinline__ void row_acc(const float4* __restrict__ r4,
                                        const uint2*  __restrict__ rh,
                                        size_t s, int f, float p, float4& acc){
  if constexpr (M == 1){
    uint2 v = rh[s*16 + f];
    half2* ph = (half2*)&v;
    float2 fa = __half22float2(ph[0]);
    float2 fb = __half22float2(ph[1]);
    acc.x = fmaf(fa.x, p, acc.x); acc.y = fmaf(fa.y, p, acc.y);
    acc.z = fmaf(fb.x, p, acc.z); acc.w = fmaf(fb.y, p, acc.w);
  } else {
    float4 r = r4[s*16 + f];
    acc.x = fmaf(r.x, p, acc.x); acc.y = fmaf(r.y, p, acc.y);
    acc.z = fmaf(r.z, p, acc.z); acc.w = fmaf(r.w, p, acc.w);
  }
}

// GCN: h1 = relu((sum_s hs[s] + hs[i]) * dinv[i] + gcn_b)
template<int M>
__global__ __launch_bounds__(256) void k_gcn_gather(const int* __restrict__ csr,
                                                    const int* __restrict__ off,
                                                    const float4* __restrict__ hs4,
                                                    const uint2*  __restrict__ hsH,
                                                    const float* __restrict__ dinv,
                                                    const float4* __restrict__ gcn_b4,
                                                    float4* __restrict__ h1_4){
  int node = blockIdx.x*4 + (threadIdx.x >> 6);
  if (node >= NN) return;
  int lane = threadIdx.x & 63;
  int q = lane >> 4, f = lane & 15;
  int beg = off[node], end = off[node+1];
  float4 acc = {0.f,0.f,0.f,0.f};
  for (int c = beg; c < end; c += 64){
    int n = end - c; if (n > 64) n = 64;
    int idx = (lane < n) ? csr[c + lane] : 0;
    for (int k = 0; k < n; k += 16){
      int e0 = k + q, e1 = k + 4 + q, e2 = k + 8 + q, e3 = k + 12 + q;
      int s0 = __shfl(idx, e0, 64);
      int s1 = __shfl(idx, e1, 64);
      int s2 = __shfl(idx, e2, 64);
      int s3 = __shfl(idx, e3, 64);
      if (e0 < n) row_acc<M>(hs4, hsH, (size_t)s0, f, 1.f, acc);
      if (e1 < n) row_acc<M>(hs4, hsH, (size_t)s1, f, 1.f, acc);
      if (e2 < n) row_acc<M>(hs4, hsH, (size_t)s2, f, 1.f, acc);
      if (e3 < n) row_acc<M>(hs4, hsH, (size_t)s3, f, 1.f, acc);
    }
  }
  #pragma unroll
  for (int o = 16; o <= 32; o <<= 1){
    acc.x += __shfl_xor(acc.x, o, 64);
    acc.y += __shfl_xor(acc.y, o, 64);
    acc.z += __shfl_xor(acc.z, o, 64);
    acc.w += __shfl_xor(acc.w, o, 64);
  }
  if (q == 0){
    float4 s  = hs4[(size_t)node*16 + f];      // self term from f32
    float  di = dinv[node];
    float4 b4 = gcn_b4[f];
    float4 o;
    o.x = fmaxf((acc.x + s.x)*di + b4.x, 0.f);
    o.y = fmaxf((acc.y + s.y)*di + b4.y, 0.f);
    o.z = fmaxf((acc.z + s.z)*di + b4.z, 0.f);
    o.w = fmaxf((acc.w + s.w)*di + b4.w, 0.f);
    h1_4[(size_t)node*16 + f] = o;
  }
}

// GAT: fused segment softmax + weighted gather (+fp16 mirror of h2 when M==1)
template<int M>
__global__ __launch_bounds__(256) void k_gat_gather(const int* __restrict__ csr,
                                                    const int* __restrict__ off,
                                                    const float* __restrict__ as_,
                                                    const float* __restrict__ ad_,
                                                    const float4* __restrict__ h2pre4,
                                                    const uint2*  __restrict__ h2preH,
                                                    const float4* __restrict__ gat_b4,
                                                    float4* __restrict__ h2_4,
                                                    uint2* __restrict__ h2H){
  int node = blockIdx.x*4 + (threadIdx.x >> 6);
  if (node >= NN) return;
  int lane = threadIdx.x & 63;
  int q = lane >> 4, f = lane & 15;
  int beg = off[node], end = off[node+1];
  float adi = ad_[node];
  float eself = lrelu(as_[node] + adi);
  float lm = -1e30f;
  for (int c = beg + lane; c < end; c += 64)
    lm = fmaxf(lm, lrelu(as_[csr[c]] + adi));
  #pragma unroll
  for (int o = 32; o > 0; o >>= 1) lm = fmaxf(lm, __shfl_xor(lm, o, 64));
  float m = fmaxf(eself, lm);
  float ps = expf(eself - m);
  float ssum = 0.f;
  float4 acc = {0.f,0.f,0.f,0.f};
  for (int c = beg; c < end; c += 64){
    int n = end - c; if (n > 64) n = 64;
    int idx = 0; float pv = 0.f;
    if (lane < n){
      idx = csr[c + lane];
      pv = expf(lrelu(as_[idx] + adi) - m);
    }
    for (int k = 0; k < n; k += 16){
      int e0 = k + q, e1 = k + 4 + q, e2 = k + 8 + q, e3 = k + 12 + q;
      int s0 = __shfl(idx, e0, 64); float p0 = __shfl(pv, e0, 64);
      int s1 = __shfl(idx, e1, 64); float p1 = __shfl(pv, e1, 64);
      int s2 = __shfl(idx, e2, 64); float p2 = __shfl(pv, e2, 64);
      int s3 = __shfl(idx, e3, 64); float p3 = __shfl(pv, e3, 64);
      if (e0 < n){ row_acc<M>(h2pre4, h2preH, (size_t)s0, f, p0, acc); ssum += p0; }
      if (e1 < n){ row_acc<M>(h2pre4, h2preH, (size_t)s1, f, p1, acc); ssum += p1; }
      if (e2 < n){ row_acc<M>(h2pre4, h2preH, (size_t)s2, f, p2, acc); ssum += p2; }
      if (e3 < n){ row_acc<M>(h2pre4, h2preH, (size_t)s3, f, p3, acc); ssum += p3; }
    }
  }
  #pragma unroll
  for (int o = 16; o <= 32; o <<= 1){
    acc.x += __shfl_xor(acc.x, o, 64);
    acc.y += __shfl_xor(acc.y, o, 64);
    acc.z += __shfl_xor(acc.z, o, 64);
    acc.w += __shfl_xor(acc.w, o, 64);
    ssum  += __shfl_xor(ssum,  o, 64);
  }
  if (q == 0){
    float inv = 1.f/(ssum + ps);
    float4 h0 = h2pre4[(size_t)node*16 + f];   // self term from f32
    float4 b4 = gat_b4[f];
    float4 o;
    o.x = fmaxf((acc.x + h0.x*ps)*inv + b4.x, 0.f);
    o.y = fmaxf((acc.y + h0.y*ps)*inv + b4.y, 0.f);
    o.z = fmaxf((acc.z + h0.z*ps)*inv + b4.z, 0.f);
    o.w = fmaxf((acc.w + h0.w*ps)*inv + b4.w, 0.f);
    h2_4[(size_t)node*16 + f] = o;
    if constexpr (M == 1){
      union { half2 h[2]; uint2 u; } pk;
      pk.h[0] = __floats2half2_rn(o.x, o.y);
      pk.h[1] = __floats2half2_rn(o.z, o.w);
      h2H[(size_t)node*16 + f] = pk.u;
    }
  }
}

// SAGE gather: mean of h2 rows
template<int M>
__global__ __launch_bounds__(256) void k_sage_gather(const int* __restrict__ csr,
                                                     const int* __restrict__ off,
                                                     const int* __restrict__ cnt,
                                                     const float4* __restrict__ h2_4,
                                                     const uint2*  __restrict__ h2H,
                                                     float4* __restrict__ mean4){
  int node = blockIdx.x*4 + (threadIdx.x >> 6);
  if (node >= NN) return;
  int lane = threadIdx.x & 63;
  int q = lane >> 4, f = lane & 15;
  int beg = off[node], end = off[node+1];
  float4 acc = {0.f,0.f,0.f,0.f};
  for (int c = beg; c < end; c += 64){
    int n = end - c; if (n > 64) n = 64;
    int idx = (lane < n) ? csr[c + lane] : 0;
    for (int k = 0; k < n; k += 16){
      int e0 = k + q, e1 = k + 4 + q, e2 = k + 8 + q, e3 = k + 12 + q;
      int s0 = __shfl(idx, e0, 64);
      int s1 = __shfl(idx, e1, 64);
      int s2 = __shfl(idx, e2, 64);
      int s3 = __shfl(idx, e3, 64);
      if (e0 < n) row_acc<M>(h2_4, h2H, (size_t)s0, f, 1.f, acc);
      if (e1 < n) row_acc<M>(h2_4, h2H, (size_t)s1, f, 1.f, acc);
      if (e2 < n) row_acc<M>(h2_4, h2H, (size_t)s2, f, 1.f, acc);
      if (e3 < n) row_acc<M>(h2_4, h2H, (size_t)s3, f, 1.f, acc);
    }
  }
  #pragma unroll
  for (int o = 16; o <= 32; o <<= 1){
    acc.x += __shfl_xor(acc.x, o, 64);
    acc.y += __shfl_xor(acc.y, o, 64);
    acc.z += __shfl_xor(acc.z, o, 64);
    acc.w += __shfl_xor(acc.w, o, 64);
  }
  if (q == 0){
    float inv = 1.f/fmaxf((float)cnt[node], 1.f);
    float4 o = {acc.x*inv, acc.y*inv, acc.z*inv, acc.w*inv};
    mean4[(size_t)node*16 + f] = o;
  }
}

// ---------------- launch ----------------

extern "C" void kernel_launch(void* const* d_in, const int* in_sizes, int n_in,
                              void* d_out, int out_size, void* d_ws, size_t ws_size,
                              hipStream_t stream) {
  const float* x      = (const float*)d_in[0];
  const int*   ei     = (const int*)d_in[1];
  const int*   src    = ei;
  const int*   dstp   = ei + NE;
  const float* gcn_w  = (const float*)d_in[2];
  const float* gcn_b  = (const float*)d_in[3];
  const float* gat_w  = (const float*)d_in[4];
  const float* att_s  = (const float*)d_in[5];
  const float* att_d  = (const float*)d_in[6];
  const float* gat_b  = (const float*)d_in[7];
  const float* s_wl   = (const float*)d_in[8];
  const float* s_wr   = (const float*)d_in[9];
  const float* s_b    = (const float*)d_in[10];
  float* outp = (float*)d_out;

  // workspace layout (4-byte words)
  int*   cnt  = (int*)d_ws;          // N
  int*   cur  = cnt + NN;            // N
  int*   off  = cur + NN;            // N+1
  int*   part = off + NN + 1;        // 1024 (pad)
  float* dinv = (float*)(part + 1024);
  float* as_  = dinv + NN;
  float* ad_  = as_  + NN;
  int*   csr  = (int*)(ad_ + NN);    // NE
  float* BIG0 = (float*)(csr + NE);  // N*HID f32
  float* BIG1 = BIG0 + (size_t)NN*HID;

  size_t base_words = (size_t)6*NN + 1 + 1024 + NE;
  size_t need2 = (base_words + (size_t)2*NN*HID)*4;   // 2 big f32 ws buffers

  const size_t NH = (size_t)NN*HID;
  const int B = 256;
  const int GROWS = (NN + 31)/32;
  const int GG = (NN + 3)/4;
  const int NC4 = (int)(NH/4);

  // CSR build
  k_zero_i<<<(2*NN + B-1)/B, B, 0, stream>>>(cnt, 2*NN);
  k_count <<<(NE + B-1)/B, B, 0, stream>>>(dstp, cnt);
  k_dinv  <<<(NN + B-1)/B, B, 0, stream>>>(cnt, dinv);
  k_scan1 <<<NBLK1, B, 0, stream>>>(cnt, off, part);
  k_scan2 <<<1, 128, 0, stream>>>(part);
  k_scan3 <<<(NN + B-1)/B, B, 0, stream>>>(off, part);
  k_fill8 <<<NPASS*((NE + B-1)/B), B, 0, stream>>>(src, dstp, off, cur, csr);

  if (ws_size >= need2){
    // fp16 tier: f32 ping-pong in ws; fp16 mirrors live in d_out
    float* P_hs    = BIG0;
    float* P_h1    = BIG1;
    float* P_h2pre = BIG0;                 // hs dead after gcn_gather
    float* P_h2    = BIG1;                 // h1 dead after gat_lin
    float* P_mean  = BIG0;                 // h2pre dead after gat_gather
    __half* HS_H    = (__half*)outp;       // NH halfs (first half of d_out)
    __half* H2PRE_H = (__half*)outp + NH;  // NH halfs (second half)
    __half* H2_H    = (__half*)outp;       // reuse hsH slot after gcn_gather

    // GCN
    k_gemm_in<<<GROWS, B, 0, stream>>>(x, gcn_w, dinv, P_hs);
    k_cast_h <<<(NC4 + B-1)/B, B, 0, stream>>>((const float4*)P_hs, (uint2*)HS_H, NC4);
    k_gcn_gather<1><<<GG, B, 0, stream>>>(csr, off, (const float4*)P_hs,
        (const uint2*)HS_H, dinv, (const float4*)gcn_b, (float4*)P_h1);

    // GAT
    k_gat_lin<<<GROWS, B, 0, stream>>>(P_h1, gat_w, att_s, att_d, P_h2pre, as_, ad_);
    k_cast_h <<<(NC4 + B-1)/B, B, 0, stream>>>((const float4*)P_h2pre, (uint2*)H2PRE_H, NC4);
    k_gat_gather<1><<<GG, B, 0, stream>>>(csr, off, as_, ad_,
        (const float4*)P_h2pre, (const uint2*)H2PRE_H, (const float4*)gat_b,
        (float4*)P_h2, (uint2*)H2_H);

    // SAGE
    k_sage_gather<1><<<GG, B, 0, stream>>>(csr, off, cnt,
        (const float4*)P_h2, (const uint2*)H2_H, (float4*)P_mean);
    k_sage_dense<<<GROWS, B, 0, stream>>>(P_mean, P_h2, s_wl, s_wr, s_b, outp);
  } else {
    // f32 fallback: d_out time-shared as a big buffer
    float* P_hs    = outp;
    float* P_h1    = BIG0;
    float* P_h2pre = outp;
    float* P_h2    = BIG0;
    float* P_mean  = outp;

    k_gemm_in<<<GROWS, B, 0, stream>>>(x, gcn_w, dinv, P_hs);
    k_gcn_gather<0><<<GG, B, 0, stream>>>(csr, off, (const float4*)P_hs,
        nullptr, dinv, (const float4*)gcn_b, (float4*)P_h1);
    k_gat_lin<<<GROWS, B, 0, stream>>>(P_h1, gat_w, att_s, att_d, P_h2pre, as_, ad_);
    k_gat_gather<0><<<GG, B, 0, stream>>>(csr, off, as_, ad_,
        (const float4*)P_h2pre, nullptr, (const float4*)gat_b, (float4*)P_h2, nullptr);
    k_sage_gather<0><<<GG, B, 0, stream>>>(csr, off, cnt,
        (const float4*)P_h2, nullptr, (float4*)P_mean);
    k_sage_dense<<<GROWS, B, 0, stream>>>(P_mean, P_h2, s_wl, s_wr, s_b, outp);
  }
}

// Round 8
// 403.023 us; speedup vs baseline: 2.7886x; 1.0300x over previous
//
#include <hip/hip_runtime.h>
#include <hip/hip_fp16.h>
#include <math.h>

#define NN 100000
#define NE 1600000
#define INF_ 128
#define HID 64
#define NEG 0.2f
#define NBLK1 98     // ceil(NN/1024) for scan
#define NPASS 8      // XCD count
#define DRNG 12500   // NN/NPASS

__device__ __forceinline__ float lrelu(float v){ return v > 0.f ? v : NEG*v; }

// ---------------- CSR build ----------------

__global__ void k_zero_i(int* p, int n){
  int i = blockIdx.x*blockDim.x + threadIdx.x;
  if (i < n) p[i] = 0;
}

// XCD-affine count: block b counts only dst-range (b&7) -> atomics stay in one L2
__global__ __launch_bounds__(256) void k_count8(const int* __restrict__ dst,
                                                int* __restrict__ cnt){
  int pass  = blockIdx.x & (NPASS-1);
  int chunk = blockIdx.x >> 3;
  int e = chunk*256 + threadIdx.x;
  if (e >= NE) return;
  int d = dst[e];
  if ((unsigned)(d - pass*DRNG) >= (unsigned)DRNG) return;
  atomicAdd(&cnt[d], 1);
}

// block scan; also emits dinv = rsqrt(cnt+1) (folds old k_dinv)
__global__ __launch_bounds__(256) void k_scan1(const int* __restrict__ cnt,
                                               int* __restrict__ off,
                                               int* __restrict__ part,
                                               float* __restrict__ dinv){
  __shared__ int l[256];
  int t = threadIdx.x;
  int base = blockIdx.x*1024 + t*4;
  int a0 = (base+0 < NN) ? cnt[base+0] : 0;
  int a1 = (base+1 < NN) ? cnt[base+1] : 0;
  int a2 = (base+2 < NN) ? cnt[base+2] : 0;
  int a3 = (base+3 < NN) ? cnt[base+3] : 0;
  if (base+0 < NN) dinv[base+0] = rsqrtf((float)a0 + 1.f);
  if (base+1 < NN) dinv[base+1] = rsqrtf((float)a1 + 1.f);
  if (base+2 < NN) dinv[base+2] = rsqrtf((float)a2 + 1.f);
  if (base+3 < NN) dinv[base+3] = rsqrtf((float)a3 + 1.f);
  int s = a0+a1+a2+a3;
  l[t] = s; __syncthreads();
  for (int o = 1; o < 256; o <<= 1){
    int v = (t >= o) ? l[t-o] : 0;
    __syncthreads();
    l[t] += v;
    __syncthreads();
  }
  if (t == 255) part[blockIdx.x] = l[255];
  int e0 = l[t] - s;
  if (base+0 < NN) off[base+0] = e0;
  if (base+1 < NN) off[base+1] = e0 + a0;
  if (base+2 < NN) off[base+2] = e0 + a0 + a1;
  if (base+3 < NN) off[base+3] = e0 + a0 + a1 + a2;
}

__global__ __launch_bounds__(128) void k_scan2(int* part){
  __shared__ int l[128];
  int t = threadIdx.x;
  int v = (t < NBLK1) ? part[t] : 0;
  l[t] = v; __syncthreads();
  for (int o = 1; o < 128; o <<= 1){
    int u = (t >= o) ? l[t-o] : 0;
    __syncthreads();
    l[t] += u;
    __syncthreads();
  }
  if (t < NBLK1) part[t] = l[t] - v;
}

__global__ void k_scan3(int* off, const int* __restrict__ part){
  int i = blockIdx.x*blockDim.x + threadIdx.x;
  if (i < NN) off[i] += part[i >> 10];
  if (i == 0) off[NN] = NE;
}

// XCD-affine fill
__global__ __launch_bounds__(256) void k_fill8(const int* __restrict__ src,
                                               const int* __restrict__ dst,
                                               const int* __restrict__ off,
                                               int* cur, int* __restrict__ csr){
  int pass  = blockIdx.x & (NPASS-1);
  int chunk = blockIdx.x >> 3;
  int e = chunk*256 + threadIdx.x;
  if (e >= NE) return;
  int d = dst[e];
  if ((unsigned)(d - pass*DRNG) >= (unsigned)DRNG) return;
  int p = atomicAdd(&cur[d], 1);
  csr[off[d] + p] = src[e];
}

// ---------------- dense linears: 8 rows/wave, 16-reg weight chunks ----------------

// hs = (x @ w) * dinv  (+fp16 mirror when M==1)
template<int M>
__global__ __launch_bounds__(256, 4) void k_gemm_in(const float* __restrict__ x,
                                                    const float* __restrict__ w,
                                                    const float* __restrict__ dinv,
                                                    float* __restrict__ hs,
                                                    __half* __restrict__ hsH){
  __shared__ float xl[4][8][INF_];
  const int wave = threadIdx.x >> 6, lane = threadIdx.x & 63;
  int rb = blockIdx.x*32 + wave*8;
  if (rb >= NN) return;
  #pragma unroll
  for (int r = 0; r < 8; ++r){
    xl[wave][r][lane]      = x[(size_t)(rb+r)*INF_ + lane];
    xl[wave][r][lane + 64] = x[(size_t)(rb+r)*INF_ + lane + 64];
  }
  float acc[8] = {0.f,0.f,0.f,0.f,0.f,0.f,0.f,0.f};
  #pragma unroll
  for (int c = 0; c < 8; ++c){
    float wv[16];
    #pragma unroll
    for (int j = 0; j < 16; ++j) wv[j] = w[(c*16 + j)*HID + lane];
    #pragma unroll
    for (int r = 0; r < 8; ++r)
      #pragma unroll
      for (int j = 0; j < 16; ++j)
        acc[r] = fmaf(xl[wave][r][c*16 + j], wv[j], acc[r]);
  }
  #pragma unroll
  for (int r = 0; r < 8; ++r){
    float v = acc[r]*dinv[rb+r];
    hs[(size_t)(rb+r)*HID + lane] = v;
    if constexpr (M == 1) hsH[(size_t)(rb+r)*HID + lane] = __float2half(v);
  }
}

// h2pre = h1 @ gat_w (+fp16 mirror when M==1); as_/ad_ via LDS-transpose dot
template<int M>
__global__ __launch_bounds__(256, 4) void k_gat_lin(const float* __restrict__ h1,
                                                    const float* __restrict__ w,
                                                    const float* __restrict__ atts,
                                                    const float* __restrict__ attd,
                                                    float* __restrict__ h2pre,
                                                    __half* __restrict__ h2preH,
                                                    float* __restrict__ as_,
                                                    float* __restrict__ ad_){
  __shared__ float xl[4][8][HID];
  __shared__ float asl[HID], adl[HID];
  if (threadIdx.x < HID){
    asl[threadIdx.x] = atts[threadIdx.x];
    adl[threadIdx.x] = attd[threadIdx.x];
  }
  __syncthreads();
  const int wave = threadIdx.x >> 6, lane = threadIdx.x & 63;
  int rb = blockIdx.x*32 + wave*8;
  if (rb >= NN) return;
  #pragma unroll
  for (int r = 0; r < 8; ++r)
    xl[wave][r][lane] = h1[(size_t)(rb+r)*HID + lane];
  float acc[8] = {0.f,0.f,0.f,0.f,0.f,0.f,0.f,0.f};
  #pragma unroll
  for (int c = 0; c < 4; ++c){
    float wv[16];
    #pragma unroll
    for (int j = 0; j < 16; ++j) wv[j] = w[(c*16 + j)*HID + lane];
    #pragma unroll
    for (int r = 0; r < 8; ++r)
      #pragma unroll
      for (int j = 0; j < 16; ++j)
        acc[r] = fmaf(xl[wave][r][c*16 + j], wv[j], acc[r]);
  }
  #pragma unroll
  for (int r = 0; r < 8; ++r){
    h2pre[(size_t)(rb+r)*HID + lane] = acc[r];
    if constexpr (M == 1) h2preH[(size_t)(rb+r)*HID + lane] = __float2half(acc[r]);
    xl[wave][r][lane] = acc[r];          // wave-private; staging already consumed
  }
  int rr = lane >> 3, t = lane & 7;
  float vs = 0.f, vd = 0.f;
  #pragma unroll
  for (int i = 0; i < 8; ++i){
    float v = xl[wave][rr][t + 8*i];
    vs = fmaf(v, asl[t + 8*i], vs);
    vd = fmaf(v, adl[t + 8*i], vd);
  }
  #pragma unroll
  for (int o = 1; o < 8; o <<= 1){
    vs += __shfl_xor(vs, o, 64);
    vd += __shfl_xor(vd, o, 64);
  }
  if (t == 0){ as_[rb + rr] = vs; ad_[rb + rr] = vd; }
}

// out = mean@wl + h2@wr + b   (mean/out may alias in fallback; row-local RAW safe)
__global__ __launch_bounds__(256, 4) void k_sage_dense(const float* mean,
                                                       const float* __restrict__ h2,
                                                       const float* __restrict__ wlh,
                                                       const float* __restrict__ wrh,
                                                       const float* __restrict__ b,
                                                       float* out){
  __shared__ float ml[4][8][HID];
  __shared__ float hl[4][8][HID];
  const int wave = threadIdx.x >> 6, lane = threadIdx.x & 63;
  int rb = blockIdx.x*32 + wave*8;
  if (rb >= NN) return;
  float bl = b[lane];
  #pragma unroll
  for (int r = 0; r < 8; ++r){
    ml[wave][r][lane] = mean[(size_t)(rb+r)*HID + lane];
    hl[wave][r][lane] = h2[(size_t)(rb+r)*HID + lane];
  }
  float acc[8] = {bl,bl,bl,bl,bl,bl,bl,bl};
  #pragma unroll
  for (int c = 0; c < 4; ++c){
    float wvl[16], wvr[16];
    #pragma unroll
    for (int j = 0; j < 16; ++j){
      wvl[j] = wlh[(c*16 + j)*HID + lane];
      wvr[j] = wrh[(c*16 + j)*HID + lane];
    }
    #pragma unroll
    for (int r = 0; r < 8; ++r)
      #pragma unroll
      for (int j = 0; j < 16; ++j){
        acc[r] = fmaf(ml[wave][r][c*16 + j], wvl[j], acc[r]);
        acc[r] = fmaf(hl[wave][r][c*16 + j], wvr[j], acc[r]);
      }
  }
  #pragma unroll
  for (int r = 0; r < 8; ++r)
    out[(size_t)(rb+r)*HID + lane] = acc[r];
}

// ---------------- gathers: 4-row-slot, 16 rows in flight; M=1 -> fp16 rows ----

template<int M>
__device__ __forceinline__ void row_acc(const float4* __restrict__ r4,
                                        const uint2*  __restrict__ rh,
                                        size_t s, int f, float p, float4& acc){
  if constexpr (M == 1){
    uint2 v = rh[s*16 + f];
    half2* ph = (half2*)&v;
    float2 fa = __half22float2(ph[0]);
    float2 fb = __half22float2(ph[1]);
    acc.x = fmaf(fa.x, p, acc.x); acc.y = fmaf(fa.y, p, acc.y);
    acc.z = fmaf(fb.x, p, acc.z); acc.w = fmaf(fb.y, p, acc.w);
  } else {
    float4 r = r4[s*16 + f];
    acc.x = fmaf(r.x, p, acc.x); acc.y = fmaf(r.y, p, acc.y);
    acc.z = fmaf(r.z, p, acc.z); acc.w = fmaf(r.w, p, acc.w);
  }
}

// GCN: h1 = relu((sum_s hs[s] + hs[i]) * dinv[i] + gcn_b)
template<int M>
__global__ __launch_bounds__(256) void k_gcn_gather(const int* __restrict__ csr,
                                                    const int* __restrict__ off,
                                                    const float4* __restrict__ hs4,
                                                    const uint2*  __restrict__ hsH,
                                                    const float* __restrict__ dinv,
                                                    const float4* __restrict__ gcn_b4,
                                                    float4* __restrict__ h1_4){
  int node = blockIdx.x*4 + (threadIdx.x >> 6);
  if (node >= NN) return;
  int lane = threadIdx.x & 63;
  int q = lane >> 4, f = lane & 15;
  int beg = off[node], end = off[node+1];
  float4 acc = {0.f,0.f,0.f,0.f};
  for (int c = beg; c < end; c += 64){
    int n = end - c; if (n > 64) n = 64;
    int idx = (lane < n) ? csr[c + lane] : 0;
    for (int k = 0; k < n; k += 16){
      int e0 = k + q, e1 = k + 4 + q, e2 = k + 8 + q, e3 = k + 12 + q;
      int s0 = __shfl(idx, e0, 64);
      int s1 = __shfl(idx, e1, 64);
      int s2 = __shfl(idx, e2, 64);
      int s3 = __shfl(idx, e3, 64);
      if (e0 < n) row_acc<M>(hs4, hsH, (size_t)s0, f, 1.f, acc);
      if (e1 < n) row_acc<M>(hs4, hsH, (size_t)s1, f, 1.f, acc);
      if (e2 < n) row_acc<M>(hs4, hsH, (size_t)s2, f, 1.f, acc);
      if (e3 < n) row_acc<M>(hs4, hsH, (size_t)s3, f, 1.f, acc);
    }
  }
  #pragma unroll
  for (int o = 16; o <= 32; o <<= 1){
    acc.x += __shfl_xor(acc.x, o, 64);
    acc.y += __shfl_xor(acc.y, o, 64);
    acc.z += __shfl_xor(acc.z, o, 64);
    acc.w += __shfl_xor(acc.w, o, 64);
  }
  if (q == 0){
    float4 s  = hs4[(size_t)node*16 + f];      // self term from f32
    float  di = dinv[node];
    float4 b4 = gcn_b4[f];
    float4 o;
    o.x = fmaxf((acc.x + s.x)*di + b4.x, 0.f);
    o.y = fmaxf((acc.y + s.y)*di + b4.y, 0.f);
    o.z = fmaxf((acc.z + s.z)*di + b4.z, 0.f);
    o.w = fmaxf((acc.w + s.w)*di + b4.w, 0.f);
    h1_4[(size_t)node*16 + f] = o;
  }
}

// GAT: fused segment softmax + weighted gather (+fp16 mirror of h2 when M==1)
template<int M>
__global__ __launch_bounds__(256) void k_gat_gather(const int* __restrict__ csr,
                                                    const int* __restrict__ off,
                                                    const float* __restrict__ as_,
                                                    const float* __restrict__ ad_,
                                                    const float4* __restrict__ h2pre4,
                                                    const uint2*  __restrict__ h2preH,
                                                    const float4* __restrict__ gat_b4,
                                                    float4* __restrict__ h2_4,
                                                    uint2* __restrict__ h2H){
  int node = blockIdx.x*4 + (threadIdx.x >> 6);
  if (node >= NN) return;
  int lane = threadIdx.x & 63;
  int q = lane >> 4, f = lane & 15;
  int beg = off[node], end = off[node+1];
  float adi = ad_[node];
  float eself = lrelu(as_[node] + adi);
  float lm = -1e30f;
  for (int c = beg + lane; c < end; c += 64)
    lm = fmaxf(lm, lrelu(as_[csr[c]] + adi));
  #pragma unroll
  for (int o = 32; o > 0; o >>= 1) lm = fmaxf(lm, __shfl_xor(lm, o, 64));
  float m = fmaxf(eself, lm);
  float ps = expf(eself - m);
  float ssum = 0.f;
  float4 acc = {0.f,0.f,0.f,0.f};
  for (int c = beg; c < end; c += 64){
    int n = end - c; if (n > 64) n = 64;
    int idx = 0; float pv = 0.f;
    if (lane < n){
      idx = csr[c + lane];
      pv = expf(lrelu(as_[idx] + adi) - m);
    }
    for (int k = 0; k < n; k += 16){
      int e0 = k + q, e1 = k + 4 + q, e2 = k + 8 + q, e3 = k + 12 + q;
      int s0 = __shfl(idx, e0, 64); float p0 = __shfl(pv, e0, 64);
      int s1 = __shfl(idx, e1, 64); float p1 = __shfl(pv, e1, 64);
      int s2 = __shfl(idx, e2, 64); float p2 = __shfl(pv, e2, 64);
      int s3 = __shfl(idx, e3, 64); float p3 = __shfl(pv, e3, 64);
      if (e0 < n){ row_acc<M>(h2pre4, h2preH, (size_t)s0, f, p0, acc); ssum += p0; }
      if (e1 < n){ row_acc<M>(h2pre4, h2preH, (size_t)s1, f, p1, acc); ssum += p1; }
      if (e2 < n){ row_acc<M>(h2pre4, h2preH, (size_t)s2, f, p2, acc); ssum += p2; }
      if (e3 < n){ row_acc<M>(h2pre4, h2preH, (size_t)s3, f, p3, acc); ssum += p3; }
    }
  }
  #pragma unroll
  for (int o = 16; o <= 32; o <<= 1){
    acc.x += __shfl_xor(acc.x, o, 64);
    acc.y += __shfl_xor(acc.y, o, 64);
    acc.z += __shfl_xor(acc.z, o, 64);
    acc.w += __shfl_xor(acc.w, o, 64);
    ssum  += __shfl_xor(ssum,  o, 64);
  }
  if (q == 0){
    float inv = 1.f/(ssum + ps);
    float4 h0 = h2pre4[(size_t)node*16 + f];   // self term from f32
    float4 b4 = gat_b4[f];
    float4 o;
    o.x = fmaxf((acc.x + h0.x*ps)*inv + b4.x, 0.f);
    o.y = fmaxf((acc.y + h0.y*ps)*inv + b4.y, 0.f);
    o.z = fmaxf((acc.z + h0.z*ps)*inv + b4.z, 0.f);
    o.w = fmaxf((acc.w + h0.w*ps)*inv + b4.w, 0.f);
    h2_4[(size_t)node*16 + f] = o;
    if constexpr (M == 1){
      union { half2 h[2]; uint2 u; } pk;
      pk.h[0] = __floats2half2_rn(o.x, o.y);
      pk.h[1] = __floats2half2_rn(o.z, o.w);
      h2H[(size_t)node*16 + f] = pk.u;
    }
  }
}

// SAGE gather: mean of h2 rows
template<int M>
__global__ __launch_bounds__(256) void k_sage_gather(const int* __restrict__ csr,
                                                     const int* __restrict__ off,
                                                     const int* __restrict__ cnt,
                                                     const float4* __restrict__ h2_4,
                                                     const uint2*  __restrict__ h2H,
                                                     float4* __restrict__ mean4){
  int node = blockIdx.x*4 + (threadIdx.x >> 6);
  if (node >= NN) return;
  int lane = threadIdx.x & 63;
  int q = lane >> 4, f = lane & 15;
  int beg = off[node], end = off[node+1];
  float4 acc = {0.f,0.f,0.f,0.f};
  for (int c = beg; c < end; c += 64){
    int n = end - c; if (n > 64) n = 64;
    int idx = (lane < n) ? csr[c + lane] : 0;
    for (int k = 0; k < n; k += 16){
      int e0 = k + q, e1 = k + 4 + q, e2 = k + 8 + q, e3 = k + 12 + q;
      int s0 = __shfl(idx, e0, 64);
      int s1 = __shfl(idx, e1, 64);
      int s2 = __shfl(idx, e2, 64);
      int s3 = __shfl(idx, e3, 64);
      if (e0 < n) row_acc<M>(h2_4, h2H, (size_t)s0, f, 1.f, acc);
      if (e1 < n) row_acc<M>(h2_4, h2H, (size_t)s1, f, 1.f, acc);
      if (e2 < n) row_acc<M>(h2_4, h2H, (size_t)s2, f, 1.f, acc);
      if (e3 < n) row_acc<M>(h2_4, h2H, (size_t)s3, f, 1.f, acc);
    }
  }
  #pragma unroll
  for (int o = 16; o <= 32; o <<= 1){
    acc.x += __shfl_xor(acc.x, o, 64);
    acc.y += __shfl_xor(acc.y, o, 64);
    acc.z += __shfl_xor(acc.z, o, 64);
    acc.w += __shfl_xor(acc.w, o, 64);
  }
  if (q == 0){
    float inv = 1.f/fmaxf((float)cnt[node], 1.f);
    float4 o = {acc.x*inv, acc.y*inv, acc.z*inv, acc.w*inv};
    mean4[(size_t)node*16 + f] = o;
  }
}

// ---------------- launch ----------------

extern "C" void kernel_launch(void* const* d_in, const int* in_sizes, int n_in,
                              void* d_out, int out_size, void* d_ws, size_t ws_size,
                              hipStream_t stream) {
  const float* x      = (const float*)d_in[0];
  const int*   ei     = (const int*)d_in[1];
  const int*   src    = ei;
  const int*   dstp   = ei + NE;
  const float* gcn_w  = (const float*)d_in[2];
  const float* gcn_b  = (const float*)d_in[3];
  const float* gat_w  = (const float*)d_in[4];
  const float* att_s  = (const float*)d_in[5];
  const float* att_d  = (const float*)d_in[6];
  const float* gat_b  = (const float*)d_in[7];
  const float* s_wl   = (const float*)d_in[8];
  const float* s_wr   = (const float*)d_in[9];
  const float* s_b    = (const float*)d_in[10];
  float* outp = (float*)d_out;

  // workspace layout (4-byte words)
  int*   cnt  = (int*)d_ws;          // N
  int*   cur  = cnt + NN;            // N
  int*   off  = cur + NN;            // N+1
  int*   part = off + NN + 1;        // 1024 (pad)
  float* dinv = (float*)(part + 1024);
  float* as_  = dinv + NN;
  float* ad_  = as_  + NN;
  int*   csr  = (int*)(ad_ + NN);    // NE
  float* BIG0 = (float*)(csr + NE);  // N*HID f32
  float* BIG1 = BIG0 + (size_t)NN*HID;

  size_t base_words = (size_t)6*NN + 1 + 1024 + NE;
  size_t need2 = (base_words + (size_t)2*NN*HID)*4;   // 2 big f32 ws buffers

  const size_t NH = (size_t)NN*HID;
  const int B = 256;
  const int GROWS = (NN + 31)/32;
  const int GG = (NN + 3)/4;
  const int EP = NPASS*((NE + B-1)/B);

  // CSR build
  k_zero_i<<<(2*NN + B-1)/B, B, 0, stream>>>(cnt, 2*NN);
  k_count8<<<EP, B, 0, stream>>>(dstp, cnt);
  k_scan1 <<<NBLK1, B, 0, stream>>>(cnt, off, part, dinv);
  k_scan2 <<<1, 128, 0, stream>>>(part);
  k_scan3 <<<(NN + B-1)/B, B, 0, stream>>>(off, part);
  k_fill8 <<<EP, B, 0, stream>>>(src, dstp, off, cur, csr);

  if (ws_size >= need2){
    // fp16 tier: f32 ping-pong in ws; fp16 mirrors live in d_out
    float* P_hs    = BIG0;
    float* P_h1    = BIG1;
    float* P_h2pre = BIG0;                 // hs dead after gcn_gather
    float* P_h2    = BIG1;                 // h1 dead after gat_lin
    float* P_mean  = BIG0;                 // h2pre dead after gat_gather
    __half* HS_H    = (__half*)outp;       // NH halfs (first half of d_out)
    __half* H2PRE_H = (__half*)outp + NH;  // NH halfs (second half)
    __half* H2_H    = (__half*)outp;       // reuse hsH slot after gcn_gather

    // GCN
    k_gemm_in<1><<<GROWS, B, 0, stream>>>(x, gcn_w, dinv, P_hs, HS_H);
    k_gcn_gather<1><<<GG, B, 0, stream>>>(csr, off, (const float4*)P_hs,
        (const uint2*)HS_H, dinv, (const float4*)gcn_b, (float4*)P_h1);

    // GAT
    k_gat_lin<1><<<GROWS, B, 0, stream>>>(P_h1, gat_w, att_s, att_d,
        P_h2pre, H2PRE_H, as_, ad_);
    k_gat_gather<1><<<GG, B, 0, stream>>>(csr, off, as_, ad_,
        (const float4*)P_h2pre, (const uint2*)H2PRE_H, (const float4*)gat_b,
        (float4*)P_h2, (uint2*)H2_H);

    // SAGE
    k_sage_gather<1><<<GG, B, 0, stream>>>(csr, off, cnt,
        (const float4*)P_h2, (const uint2*)H2_H, (float4*)P_mean);
    k_sage_dense<<<GROWS, B, 0, stream>>>(P_mean, P_h2, s_wl, s_wr, s_b, outp);
  } else {
    // f32 fallback: d_out time-shared as a big buffer
    float* P_hs    = outp;
    float* P_h1    = BIG0;
    float* P_h2pre = outp;
    float* P_h2    = BIG0;
    float* P_mean  = outp;

    k_gemm_in<0><<<GROWS, B, 0, stream>>>(x, gcn_w, dinv, P_hs, nullptr);
    k_gcn_gather<0><<<GG, B, 0, stream>>>(csr, off, (const float4*)P_hs,
        nullptr, dinv, (const float4*)gcn_b, (float4*)P_h1);
    k_gat_lin<0><<<GROWS, B, 0, stream>>>(P_h1, gat_w, att_s, att_d,
        P_h2pre, nullptr, as_, ad_);
    k_gat_gather<0><<<GG, B, 0, stream>>>(csr, off, as_, ad_,
        (const float4*)P_h2pre, nullptr, (const float4*)gat_b, (float4*)P_h2, nullptr);
    k_sage_gather<0><<<GG, B, 0, stream>>>(csr, off, cnt,
        (const float4*)P_h2, nullptr, (float4*)P_mean);
    k_sage_dense<<<GROWS, B, 0, stream>>>(P_mean, P_h2, s_wl, s_wr, s_b, outp);
  }
}

// Round 9
// 392.996 us; speedup vs baseline: 2.8597x; 1.0255x over previous
//
#include <hip/hip_runtime.h>
#include <hip/hip_fp16.h>
#include <math.h>

#define NN 100000
#define NE 1600000
#define INF_ 128
#define HID 64
#define NEG 0.2f
#define NBLK1 98     // ceil(NN/1024) for scan
#define NPASS 8      // XCD count
#define DRNG 12500   // NN/NPASS

__device__ __forceinline__ float lrelu(float v){ return v > 0.f ? v : NEG*v; }

// ---------------- CSR build ----------------

__global__ void k_zero_i(int* p, int n){
  int i = blockIdx.x*blockDim.x + threadIdx.x;
  if (i < n) p[i] = 0;
}

// XCD-affine count: block b counts only dst-range (b&7) -> atomics stay in one L2
__global__ __launch_bounds__(256) void k_count8(const int* __restrict__ dst,
                                                int* __restrict__ cnt){
  int pass  = blockIdx.x & (NPASS-1);
  int chunk = blockIdx.x >> 3;
  int e = chunk*256 + threadIdx.x;
  if (e >= NE) return;
  int d = dst[e];
  if ((unsigned)(d - pass*DRNG) >= (unsigned)DRNG) return;
  atomicAdd(&cnt[d], 1);
}

// block scan; also emits dinv = rsqrt(cnt+1)
__global__ __launch_bounds__(256) void k_scan1(const int* __restrict__ cnt,
                                               int* __restrict__ off,
                                               int* __restrict__ part,
                                               float* __restrict__ dinv){
  __shared__ int l[256];
  int t = threadIdx.x;
  int base = blockIdx.x*1024 + t*4;
  int a0 = (base+0 < NN) ? cnt[base+0] : 0;
  int a1 = (base+1 < NN) ? cnt[base+1] : 0;
  int a2 = (base+2 < NN) ? cnt[base+2] : 0;
  int a3 = (base+3 < NN) ? cnt[base+3] : 0;
  if (base+0 < NN) dinv[base+0] = rsqrtf((float)a0 + 1.f);
  if (base+1 < NN) dinv[base+1] = rsqrtf((float)a1 + 1.f);
  if (base+2 < NN) dinv[base+2] = rsqrtf((float)a2 + 1.f);
  if (base+3 < NN) dinv[base+3] = rsqrtf((float)a3 + 1.f);
  int s = a0+a1+a2+a3;
  l[t] = s; __syncthreads();
  for (int o = 1; o < 256; o <<= 1){
    int v = (t >= o) ? l[t-o] : 0;
    __syncthreads();
    l[t] += v;
    __syncthreads();
  }
  if (t == 255) part[blockIdx.x] = l[255];
  int e0 = l[t] - s;
  if (base+0 < NN) off[base+0] = e0;
  if (base+1 < NN) off[base+1] = e0 + a0;
  if (base+2 < NN) off[base+2] = e0 + a0 + a1;
  if (base+3 < NN) off[base+3] = e0 + a0 + a1 + a2;
}

__global__ __launch_bounds__(128) void k_scan2(int* part){
  __shared__ int l[128];
  int t = threadIdx.x;
  int v = (t < NBLK1) ? part[t] : 0;
  l[t] = v; __syncthreads();
  for (int o = 1; o < 128; o <<= 1){
    int u = (t >= o) ? l[t-o] : 0;
    __syncthreads();
    l[t] += u;
    __syncthreads();
  }
  if (t < NBLK1) part[t] = l[t] - v;
}

__global__ void k_scan3(int* off, const int* __restrict__ part){
  int i = blockIdx.x*blockDim.x + threadIdx.x;
  if (i < NN) off[i] += part[i >> 10];
}

// XCD-affine fill; off doubles as cursor. After this kernel off[d] = segment END
// of node d (gathers read beg = off[d-1], end = off[d]).
__global__ __launch_bounds__(256) void k_fill8(const int* __restrict__ src,
                                               const int* __restrict__ dst,
                                               int* off, int* __restrict__ csr){
  int pass  = blockIdx.x & (NPASS-1);
  int chunk = blockIdx.x >> 3;
  int e = chunk*256 + threadIdx.x;
  if (e >= NE) return;
  int d = dst[e];
  if ((unsigned)(d - pass*DRNG) >= (unsigned)DRNG) return;
  int p = atomicAdd(&off[d], 1);
  csr[p] = src[e];
}

// ---------------- dense linears: 8 rows/wave, 16-reg weight chunks ----------------

// hs = (x @ w) * dinv  (+fp16 mirror when M==1)
template<int M>
__global__ __launch_bounds__(256, 4) void k_gemm_in(const float* __restrict__ x,
                                                    const float* __restrict__ w,
                                                    const float* __restrict__ dinv,
                                                    float* __restrict__ hs,
                                                    __half* __restrict__ hsH){
  __shared__ float xl[4][8][INF_];
  const int wave = threadIdx.x >> 6, lane = threadIdx.x & 63;
  int rb = blockIdx.x*32 + wave*8;
  if (rb >= NN) return;
  #pragma unroll
  for (int r = 0; r < 8; ++r){
    xl[wave][r][lane]      = x[(size_t)(rb+r)*INF_ + lane];
    xl[wave][r][lane + 64] = x[(size_t)(rb+r)*INF_ + lane + 64];
  }
  float acc[8] = {0.f,0.f,0.f,0.f,0.f,0.f,0.f,0.f};
  #pragma unroll
  for (int c = 0; c < 8; ++c){
    float wv[16];
    #pragma unroll
    for (int j = 0; j < 16; ++j) wv[j] = w[(c*16 + j)*HID + lane];
    #pragma unroll
    for (int r = 0; r < 8; ++r)
      #pragma unroll
      for (int j = 0; j < 16; ++j)
        acc[r] = fmaf(xl[wave][r][c*16 + j], wv[j], acc[r]);
  }
  #pragma unroll
  for (int r = 0; r < 8; ++r){
    float v = acc[r]*dinv[rb+r];
    hs[(size_t)(rb+r)*HID + lane] = v;
    if constexpr (M == 1) hsH[(size_t)(rb+r)*HID + lane] = __float2half(v);
  }
}

// h2pre = h1 @ gat_w (+fp16 mirror when M==1); as_/ad_ via LDS-transpose dot
template<int M>
__global__ __launch_bounds__(256, 4) void k_gat_lin(const float* __restrict__ h1,
                                                    const float* __restrict__ w,
                                                    const float* __restrict__ atts,
                                                    const float* __restrict__ attd,
                                                    float* __restrict__ h2pre,
                                                    __half* __restrict__ h2preH,
                                                    float* __restrict__ as_,
                                                    float* __restrict__ ad_){
  __shared__ float xl[4][8][HID];
  __shared__ float asl[HID], adl[HID];
  if (threadIdx.x < HID){
    asl[threadIdx.x] = atts[threadIdx.x];
    adl[threadIdx.x] = attd[threadIdx.x];
  }
  __syncthreads();
  const int wave = threadIdx.x >> 6, lane = threadIdx.x & 63;
  int rb = blockIdx.x*32 + wave*8;
  if (rb >= NN) return;
  #pragma unroll
  for (int r = 0; r < 8; ++r)
    xl[wave][r][lane] = h1[(size_t)(rb+r)*HID + lane];
  float acc[8] = {0.f,0.f,0.f,0.f,0.f,0.f,0.f,0.f};
  #pragma unroll
  for (int c = 0; c < 4; ++c){
    float wv[16];
    #pragma unroll
    for (int j = 0; j < 16; ++j) wv[j] = w[(c*16 + j)*HID + lane];
    #pragma unroll
    for (int r = 0; r < 8; ++r)
      #pragma unroll
      for (int j = 0; j < 16; ++j)
        acc[r] = fmaf(xl[wave][r][c*16 + j], wv[j], acc[r]);
  }
  #pragma unroll
  for (int r = 0; r < 8; ++r){
    h2pre[(size_t)(rb+r)*HID + lane] = acc[r];
    if constexpr (M == 1) h2preH[(size_t)(rb+r)*HID + lane] = __float2half(acc[r]);
    xl[wave][r][lane] = acc[r];          // wave-private; staging already consumed
  }
  int rr = lane >> 3, t = lane & 7;
  float vs = 0.f, vd = 0.f;
  #pragma unroll
  for (int i = 0; i < 8; ++i){
    float v = xl[wave][rr][t + 8*i];
    vs = fmaf(v, asl[t + 8*i], vs);
    vd = fmaf(v, adl[t + 8*i], vd);
  }
  #pragma unroll
  for (int o = 1; o < 8; o <<= 1){
    vs += __shfl_xor(vs, o, 64);
    vd += __shfl_xor(vd, o, 64);
  }
  if (t == 0){ as_[rb + rr] = vs; ad_[rb + rr] = vd; }
}

// out = mean@wl + h2@wr + b   (mean/out may alias in fallback; row-local RAW safe)
__global__ __launch_bounds__(256, 4) void k_sage_dense(const float* mean,
                                                       const float* __restrict__ h2,
                                                       const float* __restrict__ wlh,
                                                       const float* __restrict__ wrh,
                                                       const float* __restrict__ b,
                                                       float* out){
  __shared__ float ml[4][8][HID];
  __shared__ float hl[4][8][HID];
  const int wave = threadIdx.x >> 6, lane = threadIdx.x & 63;
  int rb = blockIdx.x*32 + wave*8;
  if (rb >= NN) return;
  float bl = b[lane];
  #pragma unroll
  for (int r = 0; r < 8; ++r){
    ml[wave][r][lane] = mean[(size_t)(rb+r)*HID + lane];
    hl[wave][r][lane] = h2[(size_t)(rb+r)*HID + lane];
  }
  float acc[8] = {bl,bl,bl,bl,bl,bl,bl,bl};
  #pragma unroll
  for (int c = 0; c < 4; ++c){
    float wvl[16], wvr[16];
    #pragma unroll
    for (int j = 0; j < 16; ++j){
      wvl[j] = wlh[(c*16 + j)*HID + lane];
      wvr[j] = wrh[(c*16 + j)*HID + lane];
    }
    #pragma unroll
    for (int r = 0; r < 8; ++r)
      #pragma unroll
      for (int j = 0; j < 16; ++j){
        acc[r] = fmaf(ml[wave][r][c*16 + j], wvl[j], acc[r]);
        acc[r] = fmaf(hl[wave][r][c*16 + j], wvr[j], acc[r]);
      }
  }
  #pragma unroll
  for (int r = 0; r < 8; ++r)
    out[(size_t)(rb+r)*HID + lane] = acc[r];
}

// ---------------- gathers: 4-row-slot, 16 rows in flight; M=1 -> fp16 rows ----
// off[] holds segment ENDS: beg = (node ? off[node-1] : 0), end = off[node].

template<int M>
__device__ __forceinline__ void row_acc(const float4* __restrict__ r4,
                                        const uint2*  __restrict__ rh,
                                        size_t s, int f, float p, float4& acc){
  if constexpr (M == 1){
    uint2 v = rh[s*16 + f];
    half2* ph = (half2*)&v;
    float2 fa = __half22float2(ph[0]);
    float2 fb = __half22float2(ph[1]);
    acc.x = fmaf(fa.x, p, acc.x); acc.y = fmaf(fa.y, p, acc.y);
    acc.z = fmaf(fb.x, p, acc.z); acc.w = fmaf(fb.y, p, acc.w);
  } else {
    float4 r = r4[s*16 + f];
    acc.x = fmaf(r.x, p, acc.x); acc.y = fmaf(r.y, p, acc.y);
    acc.z = fmaf(r.z, p, acc.z); acc.w = fmaf(r.w, p, acc.w);
  }
}

// GCN: h1 = relu((sum_s hs[s] + hs[i]) * dinv[i] + gcn_b)
template<int M>
__global__ __launch_bounds__(256) void k_gcn_gather(const int* __restrict__ csr,
                                                    const int* __restrict__ off,
                                                    const float4* __restrict__ hs4,
                                                    const uint2*  __restrict__ hsH,
                                                    const float* __restrict__ dinv,
                                                    const float4* __restrict__ gcn_b4,
                                                    float4* __restrict__ h1_4){
  int node = blockIdx.x*4 + (threadIdx.x >> 6);
  if (node >= NN) return;
  int lane = threadIdx.x & 63;
  int q = lane >> 4, f = lane & 15;
  int end = off[node];
  int beg = node ? off[node-1] : 0;
  float4 acc = {0.f,0.f,0.f,0.f};
  for (int c = beg; c < end; c += 64){
    int n = end - c; if (n > 64) n = 64;
    int idx = (lane < n) ? csr[c + lane] : 0;
    for (int k = 0; k < n; k += 16){
      int e0 = k + q, e1 = k + 4 + q, e2 = k + 8 + q, e3 = k + 12 + q;
      int s0 = __shfl(idx, e0, 64);
      int s1 = __shfl(idx, e1, 64);
      int s2 = __shfl(idx, e2, 64);
      int s3 = __shfl(idx, e3, 64);
      if (e0 < n) row_acc<M>(hs4, hsH, (size_t)s0, f, 1.f, acc);
      if (e1 < n) row_acc<M>(hs4, hsH, (size_t)s1, f, 1.f, acc);
      if (e2 < n) row_acc<M>(hs4, hsH, (size_t)s2, f, 1.f, acc);
      if (e3 < n) row_acc<M>(hs4, hsH, (size_t)s3, f, 1.f, acc);
    }
  }
  #pragma unroll
  for (int o = 16; o <= 32; o <<= 1){
    acc.x += __shfl_xor(acc.x, o, 64);
    acc.y += __shfl_xor(acc.y, o, 64);
    acc.z += __shfl_xor(acc.z, o, 64);
    acc.w += __shfl_xor(acc.w, o, 64);
  }
  if (q == 0){
    float4 s  = hs4[(size_t)node*16 + f];      // self term from f32
    float  di = dinv[node];
    float4 b4 = gcn_b4[f];
    float4 o;
    o.x = fmaxf((acc.x + s.x)*di + b4.x, 0.f);
    o.y = fmaxf((acc.y + s.y)*di + b4.y, 0.f);
    o.z = fmaxf((acc.z + s.z)*di + b4.z, 0.f);
    o.w = fmaxf((acc.w + s.w)*di + b4.w, 0.f);
    h1_4[(size_t)node*16 + f] = o;
  }
}

// GAT: single-pass softmax gather. No max pass: alpha = p/s is shift-invariant,
// and e = lrelu(a_s+a_d) is O(5) << 88 (f32 exp overflow); clamp at 80 guards NaN.
template<int M>
__global__ __launch_bounds__(256) void k_gat_gather(const int* __restrict__ csr,
                                                    const int* __restrict__ off,
                                                    const float* __restrict__ as_,
                                                    const float* __restrict__ ad_,
                                                    const float4* __restrict__ h2pre4,
                                                    const uint2*  __restrict__ h2preH,
                                                    const float4* __restrict__ gat_b4,
                                                    float4* __restrict__ h2_4,
                                                    uint2* __restrict__ h2H){
  int node = blockIdx.x*4 + (threadIdx.x >> 6);
  if (node >= NN) return;
  int lane = threadIdx.x & 63;
  int q = lane >> 4, f = lane & 15;
  int end = off[node];
  int beg = node ? off[node-1] : 0;
  float adi = ad_[node];
  float ps = expf(fminf(lrelu(as_[node] + adi), 80.f));
  float ssum = 0.f;
  float4 acc = {0.f,0.f,0.f,0.f};
  for (int c = beg; c < end; c += 64){
    int n = end - c; if (n > 64) n = 64;
    int idx = 0; float pv = 0.f;
    if (lane < n){
      idx = csr[c + lane];
      pv = expf(fminf(lrelu(as_[idx] + adi), 80.f));
    }
    for (int k = 0; k < n; k += 16){
      int e0 = k + q, e1 = k + 4 + q, e2 = k + 8 + q, e3 = k + 12 + q;
      int s0 = __shfl(idx, e0, 64); float p0 = __shfl(pv, e0, 64);
      int s1 = __shfl(idx, e1, 64); float p1 = __shfl(pv, e1, 64);
      int s2 = __shfl(idx, e2, 64); float p2 = __shfl(pv, e2, 64);
      int s3 = __shfl(idx, e3, 64); float p3 = __shfl(pv, e3, 64);
      if (e0 < n){ row_acc<M>(h2pre4, h2preH, (size_t)s0, f, p0, acc); ssum += p0; }
      if (e1 < n){ row_acc<M>(h2pre4, h2preH, (size_t)s1, f, p1, acc); ssum += p1; }
      if (e2 < n){ row_acc<M>(h2pre4, h2preH, (size_t)s2, f, p2, acc); ssum += p2; }
      if (e3 < n){ row_acc<M>(h2pre4, h2preH, (size_t)s3, f, p3, acc); ssum += p3; }
    }
  }
  #pragma unroll
  for (int o = 16; o <= 32; o <<= 1){
    acc.x += __shfl_xor(acc.x, o, 64);
    acc.y += __shfl_xor(acc.y, o, 64);
    acc.z += __shfl_xor(acc.z, o, 64);
    acc.w += __shfl_xor(acc.w, o, 64);
    ssum  += __shfl_xor(ssum,  o, 64);
  }
  if (q == 0){
    float inv = 1.f/(ssum + ps);
    float4 h0 = h2pre4[(size_t)node*16 + f];   // self term from f32
    float4 b4 = gat_b4[f];
    float4 o;
    o.x = fmaxf((acc.x + h0.x*ps)*inv + b4.x, 0.f);
    o.y = fmaxf((acc.y + h0.y*ps)*inv + b4.y, 0.f);
    o.z = fmaxf((acc.z + h0.z*ps)*inv + b4.z, 0.f);
    o.w = fmaxf((acc.w + h0.w*ps)*inv + b4.w, 0.f);
    h2_4[(size_t)node*16 + f] = o;
    if constexpr (M == 1){
      union { half2 h[2]; uint2 u; } pk;
      pk.h[0] = __floats2half2_rn(o.x, o.y);
      pk.h[1] = __floats2half2_rn(o.z, o.w);
      h2H[(size_t)node*16 + f] = pk.u;
    }
  }
}

// SAGE gather: mean of h2 rows
template<int M>
__global__ __launch_bounds__(256) void k_sage_gather(const int* __restrict__ csr,
                                                     const int* __restrict__ off,
                                                     const int* __restrict__ cnt,
                                                     const float4* __restrict__ h2_4,
                                                     const uint2*  __restrict__ h2H,
                                                     float4* __restrict__ mean4){
  int node = blockIdx.x*4 + (threadIdx.x >> 6);
  if (node >= NN) return;
  int lane = threadIdx.x & 63;
  int q = lane >> 4, f = lane & 15;
  int end = off[node];
  int beg = node ? off[node-1] : 0;
  float4 acc = {0.f,0.f,0.f,0.f};
  for (int c = beg; c < end; c += 64){
    int n = end - c; if (n > 64) n = 64;
    int idx = (lane < n) ? csr[c + lane] : 0;
    for (int k = 0; k < n; k += 16){
      int e0 = k + q, e1 = k + 4 + q, e2 = k + 8 + q, e3 = k + 12 + q;
      int s0 = __shfl(idx, e0, 64);
      int s1 = __shfl(idx, e1, 64);
      int s2 = __shfl(idx, e2, 64);
      int s3 = __shfl(idx, e3, 64);
      if (e0 < n) row_acc<M>(h2_4, h2H, (size_t)s0, f, 1.f, acc);
      if (e1 < n) row_acc<M>(h2_4, h2H, (size_t)s1, f, 1.f, acc);
      if (e2 < n) row_acc<M>(h2_4, h2H, (size_t)s2, f, 1.f, acc);
      if (e3 < n) row_acc<M>(h2_4, h2H, (size_t)s3, f, 1.f, acc);
    }
  }
  #pragma unroll
  for (int o = 16; o <= 32; o <<= 1){
    acc.x += __shfl_xor(acc.x, o, 64);
    acc.y += __shfl_xor(acc.y, o, 64);
    acc.z += __shfl_xor(acc.z, o, 64);
    acc.w += __shfl_xor(acc.w, o, 64);
  }
  if (q == 0){
    float inv = 1.f/fmaxf((float)cnt[node], 1.f);
    float4 o = {acc.x*inv, acc.y*inv, acc.z*inv, acc.w*inv};
    mean4[(size_t)node*16 + f] = o;
  }
}

// ---------------- launch ----------------

extern "C" void kernel_launch(void* const* d_in, const int* in_sizes, int n_in,
                              void* d_out, int out_size, void* d_ws, size_t ws_size,
                              hipStream_t stream) {
  const float* x      = (const float*)d_in[0];
  const int*   ei     = (const int*)d_in[1];
  const int*   src    = ei;
  const int*   dstp   = ei + NE;
  const float* gcn_w  = (const float*)d_in[2];
  const float* gcn_b  = (const float*)d_in[3];
  const float* gat_w  = (const float*)d_in[4];
  const float* att_s  = (const float*)d_in[5];
  const float* att_d  = (const float*)d_in[6];
  const float* gat_b  = (const float*)d_in[7];
  const float* s_wl   = (const float*)d_in[8];
  const float* s_wr   = (const float*)d_in[9];
  const float* s_b    = (const float*)d_in[10];
  float* outp = (float*)d_out;

  // workspace layout (4-byte words)
  int*   cnt  = (int*)d_ws;          // N
  int*   off  = cnt + NN;            // N (segment ends after fill)
  int*   part = off + NN;            // 1024 (pad)
  float* dinv = (float*)(part + 1024);
  float* as_  = dinv + NN;
  float* ad_  = as_  + NN;
  int*   csr  = (int*)(ad_ + NN);    // NE
  float* BIG0 = (float*)(csr + NE);  // N*HID f32
  float* BIG1 = BIG0 + (size_t)NN*HID;

  size_t base_words = (size_t)5*NN + 1024 + NE;
  size_t need2 = (base_words + (size_t)2*NN*HID)*4;   // 2 big f32 ws buffers

  const size_t NH = (size_t)NN*HID;
  const int B = 256;
  const int GROWS = (NN + 31)/32;
  const int GG = (NN + 3)/4;
  const int EP = NPASS*((NE + B-1)/B);

  // CSR build
  k_zero_i<<<(NN + B-1)/B, B, 0, stream>>>(cnt, NN);
  k_count8<<<EP, B, 0, stream>>>(dstp, cnt);
  k_scan1 <<<NBLK1, B, 0, stream>>>(cnt, off, part, dinv);
  k_scan2 <<<1, 128, 0, stream>>>(part);
  k_scan3 <<<(NN + B-1)/B, B, 0, stream>>>(off, part);
  k_fill8 <<<EP, B, 0, stream>>>(src, dstp, off, csr);

  if (ws_size >= need2){
    // fp16 tier: f32 ping-pong in ws; fp16 mirrors live in d_out
    float* P_hs    = BIG0;
    float* P_h1    = BIG1;
    float* P_h2pre = BIG0;                 // hs dead after gcn_gather
    float* P_h2    = BIG1;                 // h1 dead after gat_lin
    float* P_mean  = BIG0;                 // h2pre dead after gat_gather
    __half* HS_H    = (__half*)outp;       // NH halfs (first half of d_out)
    __half* H2PRE_H = (__half*)outp + NH;  // NH halfs (second half)
    __half* H2_H    = (__half*)outp;       // reuse hsH slot after gcn_gather

    // GCN
    k_gemm_in<1><<<GROWS, B, 0, stream>>>(x, gcn_w, dinv, P_hs, HS_H);
    k_gcn_gather<1><<<GG, B, 0, stream>>>(csr, off, (const float4*)P_hs,
        (const uint2*)HS_H, dinv, (const float4*)gcn_b, (float4*)P_h1);

    // GAT
    k_gat_lin<1><<<GROWS, B, 0, stream>>>(P_h1, gat_w, att_s, att_d,
        P_h2pre, H2PRE_H, as_, ad_);
    k_gat_gather<1><<<GG, B, 0, stream>>>(csr, off, as_, ad_,
        (const float4*)P_h2pre, (const uint2*)H2PRE_H, (const float4*)gat_b,
        (float4*)P_h2, (uint2*)H2_H);

    // SAGE
    k_sage_gather<1><<<GG, B, 0, stream>>>(csr, off, cnt,
        (const float4*)P_h2, (const uint2*)H2_H, (float4*)P_mean);
    k_sage_dense<<<GROWS, B, 0, stream>>>(P_mean, P_h2, s_wl, s_wr, s_b, outp);
  } else {
    // f32 fallback: d_out time-shared as a big buffer
    float* P_hs    = outp;
    float* P_h1    = BIG0;
    float* P_h2pre = outp;
    float* P_h2    = BIG0;
    float* P_mean  = outp;

    k_gemm_in<0><<<GROWS, B, 0, stream>>>(x, gcn_w, dinv, P_hs, nullptr);
    k_gcn_gather<0><<<GG, B, 0, stream>>>(csr, off, (const float4*)P_hs,
        nullptr, dinv, (const float4*)gcn_b, (float4*)P_h1);
    k_gat_lin<0><<<GROWS, B, 0, stream>>>(P_h1, gat_w, att_s, att_d,
        P_h2pre, nullptr, as_, ad_);
    k_gat_gather<0><<<GG, B, 0, stream>>>(csr, off, as_, ad_,
        (const float4*)P_h2pre, nullptr, (const float4*)gat_b, (float4*)P_h2, nullptr);
    k_sage_gather<0><<<GG, B, 0, stream>>>(csr, off, cnt,
        (const float4*)P_h2, nullptr, (float4*)P_mean);
    k_sage_dense<<<GROWS, B, 0, stream>>>(P_mean, P_h2, s_wl, s_wr, s_b, outp);
  }
}

// Round 10
// 320.453 us; speedup vs baseline: 3.5071x; 1.2264x over previous
//
#include <hip/hip_runtime.h>
#include <hip/hip_fp16.h>
#include <math.h>

#define NN 100000
#define NE 1600000
#define INF_ 128
#define HID 64
#define NEG 0.2f
#define NBUK 98      // ceil(NN/1024) buckets of 1024 dst nodes
#define ACH 2048     // edges per block in bucket-build phases

__device__ __forceinline__ float lrelu(float v){ return v > 0.f ? v : NEG*v; }

// ---------------- CSR build: two-level LDS bucket sort ----------------

__global__ void k_zero_i(int* p, int n){
  int i = blockIdx.x*blockDim.x + threadIdx.x;
  if (i < n) p[i] = 0;
}

// A0: global bucket histogram (LDS-combined)
__global__ __launch_bounds__(256) void kA0(const int* __restrict__ dst,
                                           int* __restrict__ ghist){
  __shared__ int hist[NBUK];
  int t = threadIdx.x;
  if (t < NBUK) hist[t] = 0;
  __syncthreads();
  int eb = blockIdx.x*ACH;
  for (int i = t; i < ACH; i += 256){
    int e = eb + i;
    if (e < NE) atomicAdd(&hist[dst[e] >> 10], 1);
  }
  __syncthreads();
  if (t < NBUK && hist[t]) atomicAdd(&ghist[t], hist[t]);
}

// scan 98 buckets -> bases (exclusive) + cursor init; sentinels
__global__ __launch_bounds__(128) void k_scan_bk(const int* __restrict__ ghist,
                                                 int* __restrict__ bases,
                                                 int* __restrict__ cur,
                                                 int* __restrict__ off){
  __shared__ int l[128];
  int t = threadIdx.x;
  int v = (t < NBUK) ? ghist[t] : 0;
  l[t] = v; __syncthreads();
  for (int o = 1; o < 128; o <<= 1){
    int u = (t >= o) ? l[t-o] : 0;
    __syncthreads();
    l[t] += u;
    __syncthreads();
  }
  if (t < NBUK){ bases[t] = l[t] - v; cur[t] = l[t] - v; }
  if (t == 0){ bases[NBUK] = NE; off[NN] = NE; }
}

// A1: partition edges into bucket-contiguous packed words (src<<10)|(d&1023).
// Per-block chunk reservation -> block-exclusive write regions (lines written once).
__global__ __launch_bounds__(256) void kA1(const int* __restrict__ src,
                                           const int* __restrict__ dst,
                                           int* cur,
                                           unsigned* __restrict__ bucketed){
  __shared__ unsigned pk[ACH];
  __shared__ unsigned char bk[ACH];
  __shared__ int hist[NBUK], base[NBUK];
  int t = threadIdx.x;
  if (t < NBUK) hist[t] = 0;
  __syncthreads();
  int eb = blockIdx.x*ACH;
  for (int i = t; i < ACH; i += 256){
    int e = eb + i;
    if (e < NE){
      int d = dst[e];
      int b = d >> 10;
      atomicAdd(&hist[b], 1);
      pk[i] = ((unsigned)src[e] << 10) | (unsigned)(d & 1023);
      bk[i] = (unsigned char)b;
    } else bk[i] = 0xFF;
  }
  __syncthreads();
  if (t < NBUK){
    base[t] = hist[t] ? atomicAdd(&cur[t], hist[t]) : 0;
    hist[t] = 0;                      // reuse as local cursor
  }
  __syncthreads();
  for (int i = t; i < ACH; i += 256){
    if (bk[i] != 0xFF){
      int b = bk[i];
      int slot = atomicAdd(&hist[b], 1);
      bucketed[base[b] + slot] = pk[i];
    }
  }
}

// B: per-bucket CSR finalize. LDS count -> LDS scan -> off/cnt/dinv -> LDS-cursor
// scatter. csr writes confined to this block's contiguous [bbase,bend) range.
__global__ __launch_bounds__(512) void kB(const unsigned* __restrict__ bucketed,
                                          const int* __restrict__ bases,
                                          int* __restrict__ csr,
                                          int* __restrict__ off,
                                          int* __restrict__ cnt,
                                          float* __restrict__ dinv){
  __shared__ int lc[1024];
  __shared__ int lcur[1024];
  __shared__ int red[512];
  int b = blockIdx.x, t = threadIdx.x;
  int bbase = bases[b], bend = bases[b+1];
  lc[t] = 0; lc[t + 512] = 0;
  __syncthreads();
  for (int e = bbase + t; e < bend; e += 512)
    atomicAdd(&lc[bucketed[e] & 1023], 1);
  __syncthreads();
  int a0 = lc[2*t], a1 = lc[2*t+1];
  int s = a0 + a1;
  red[t] = s;
  __syncthreads();
  for (int o = 1; o < 512; o <<= 1){
    int v = (t >= o) ? red[t-o] : 0;
    __syncthreads();
    red[t] += v;
    __syncthreads();
  }
  int e0 = red[t] - s;                 // exclusive prefix for element 2t
  lcur[2*t]   = e0;
  lcur[2*t+1] = e0 + a0;
  int node = b*1024 + 2*t;
  if (node < NN){
    off[node]  = bbase + e0;
    cnt[node]  = a0;
    dinv[node] = rsqrtf((float)a0 + 1.f);
  }
  if (node + 1 < NN){
    off[node+1]  = bbase + e0 + a0;
    cnt[node+1]  = a1;
    dinv[node+1] = rsqrtf((float)a1 + 1.f);
  }
  __syncthreads();
  for (int e = bbase + t; e < bend; e += 512){
    unsigned w = bucketed[e];
    int slot = atomicAdd(&lcur[w & 1023], 1);
    csr[bbase + slot] = (int)(w >> 10);
  }
}

// ---------------- dense linears: 8 rows/wave, 16-reg weight chunks ----------------

// hs = (x @ w) * dinv  (+fp16 mirror when M==1)
template<int M>
__global__ __launch_bounds__(256, 4) void k_gemm_in(const float* __restrict__ x,
                                                    const float* __restrict__ w,
                                                    const float* __restrict__ dinv,
                                                    float* __restrict__ hs,
                                                    __half* __restrict__ hsH){
  __shared__ float xl[4][8][INF_];
  const int wave = threadIdx.x >> 6, lane = threadIdx.x & 63;
  int rb = blockIdx.x*32 + wave*8;
  if (rb >= NN) return;
  #pragma unroll
  for (int r = 0; r < 8; ++r){
    xl[wave][r][lane]      = x[(size_t)(rb+r)*INF_ + lane];
    xl[wave][r][lane + 64] = x[(size_t)(rb+r)*INF_ + lane + 64];
  }
  float acc[8] = {0.f,0.f,0.f,0.f,0.f,0.f,0.f,0.f};
  #pragma unroll
  for (int c = 0; c < 8; ++c){
    float wv[16];
    #pragma unroll
    for (int j = 0; j < 16; ++j) wv[j] = w[(c*16 + j)*HID + lane];
    #pragma unroll
    for (int r = 0; r < 8; ++r)
      #pragma unroll
      for (int j = 0; j < 16; ++j)
        acc[r] = fmaf(xl[wave][r][c*16 + j], wv[j], acc[r]);
  }
  #pragma unroll
  for (int r = 0; r < 8; ++r){
    float v = acc[r]*dinv[rb+r];
    hs[(size_t)(rb+r)*HID + lane] = v;
    if constexpr (M == 1) hsH[(size_t)(rb+r)*HID + lane] = __float2half(v);
  }
}

// h2pre = h1 @ gat_w (+fp16 mirror when M==1); as_/ad_ via LDS-transpose dot
template<int M>
__global__ __launch_bounds__(256, 4) void k_gat_lin(const float* __restrict__ h1,
                                                    const float* __restrict__ w,
                                                    const float* __restrict__ atts,
                                                    const float* __restrict__ attd,
                                                    float* __restrict__ h2pre,
                                                    __half* __restrict__ h2preH,
                                                    float* __restrict__ as_,
                                                    float* __restrict__ ad_){
  __shared__ float xl[4][8][HID];
  __shared__ float asl[HID], adl[HID];
  if (threadIdx.x < HID){
    asl[threadIdx.x] = atts[threadIdx.x];
    adl[threadIdx.x] = attd[threadIdx.x];
  }
  __syncthreads();
  const int wave = threadIdx.x >> 6, lane = threadIdx.x & 63;
  int rb = blockIdx.x*32 + wave*8;
  if (rb >= NN) return;
  #pragma unroll
  for (int r = 0; r < 8; ++r)
    xl[wave][r][lane] = h1[(size_t)(rb+r)*HID + lane];
  float acc[8] = {0.f,0.f,0.f,0.f,0.f,0.f,0.f,0.f};
  #pragma unroll
  for (int c = 0; c < 4; ++c){
    float wv[16];
    #pragma unroll
    for (int j = 0; j < 16; ++j) wv[j] = w[(c*16 + j)*HID + lane];
    #pragma unroll
    for (int r = 0; r < 8; ++r)
      #pragma unroll
      for (int j = 0; j < 16; ++j)
        acc[r] = fmaf(xl[wave][r][c*16 + j], wv[j], acc[r]);
  }
  #pragma unroll
  for (int r = 0; r < 8; ++r){
    h2pre[(size_t)(rb+r)*HID + lane] = acc[r];
    if constexpr (M == 1) h2preH[(size_t)(rb+r)*HID + lane] = __float2half(acc[r]);
    xl[wave][r][lane] = acc[r];          // wave-private; staging already consumed
  }
  int rr = lane >> 3, t = lane & 7;
  float vs = 0.f, vd = 0.f;
  #pragma unroll
  for (int i = 0; i < 8; ++i){
    float v = xl[wave][rr][t + 8*i];
    vs = fmaf(v, asl[t + 8*i], vs);
    vd = fmaf(v, adl[t + 8*i], vd);
  }
  #pragma unroll
  for (int o = 1; o < 8; o <<= 1){
    vs += __shfl_xor(vs, o, 64);
    vd += __shfl_xor(vd, o, 64);
  }
  if (t == 0){ as_[rb + rr] = vs; ad_[rb + rr] = vd; }
}

// out = mean@wl + h2@wr + b   (mean/out may alias in fallback; row-local RAW safe)
__global__ __launch_bounds__(256, 4) void k_sage_dense(const float* mean,
                                                       const float* __restrict__ h2,
                                                       const float* __restrict__ wlh,
                                                       const float* __restrict__ wrh,
                                                       const float* __restrict__ b,
                                                       float* out){
  __shared__ float ml[4][8][HID];
  __shared__ float hl[4][8][HID];
  const int wave = threadIdx.x >> 6, lane = threadIdx.x & 63;
  int rb = blockIdx.x*32 + wave*8;
  if (rb >= NN) return;
  float bl = b[lane];
  #pragma unroll
  for (int r = 0; r < 8; ++r){
    ml[wave][r][lane] = mean[(size_t)(rb+r)*HID + lane];
    hl[wave][r][lane] = h2[(size_t)(rb+r)*HID + lane];
  }
  float acc[8] = {bl,bl,bl,bl,bl,bl,bl,bl};
  #pragma unroll
  for (int c = 0; c < 4; ++c){
    float wvl[16], wvr[16];
    #pragma unroll
    for (int j = 0; j < 16; ++j){
      wvl[j] = wlh[(c*16 + j)*HID + lane];
      wvr[j] = wrh[(c*16 + j)*HID + lane];
    }
    #pragma unroll
    for (int r = 0; r < 8; ++r)
      #pragma unroll
      for (int j = 0; j < 16; ++j){
        acc[r] = fmaf(ml[wave][r][c*16 + j], wvl[j], acc[r]);
        acc[r] = fmaf(hl[wave][r][c*16 + j], wvr[j], acc[r]);
      }
  }
  #pragma unroll
  for (int r = 0; r < 8; ++r)
    out[(size_t)(rb+r)*HID + lane] = acc[r];
}

// ---------------- gathers: 4-row-slot, 16 rows in flight; M=1 -> fp16 rows ----
// off[] holds segment STARTS (NN+1 entries, off[NN]=NE).

template<int M>
__device__ __forceinline__ void row_acc(const float4* __restrict__ r4,
                                        const uint2*  __restrict__ rh,
                                        size_t s, int f, float p, float4& acc){
  if constexpr (M == 1){
    uint2 v = rh[s*16 + f];
    half2* ph = (half2*)&v;
    float2 fa = __half22float2(ph[0]);
    float2 fb = __half22float2(ph[1]);
    acc.x = fmaf(fa.x, p, acc.x); acc.y = fmaf(fa.y, p, acc.y);
    acc.z = fmaf(fb.x, p, acc.z); acc.w = fmaf(fb.y, p, acc.w);
  } else {
    float4 r = r4[s*16 + f];
    acc.x = fmaf(r.x, p, acc.x); acc.y = fmaf(r.y, p, acc.y);
    acc.z = fmaf(r.z, p, acc.z); acc.w = fmaf(r.w, p, acc.w);
  }
}

// GCN: h1 = relu((sum_s hs[s] + hs[i]) * dinv[i] + gcn_b)
template<int M>
__global__ __launch_bounds__(256) void k_gcn_gather(const int* __restrict__ csr,
                                                    const int* __restrict__ off,
                                                    const float4* __restrict__ hs4,
                                                    const uint2*  __restrict__ hsH,
                                                    const float* __restrict__ dinv,
                                                    const float4* __restrict__ gcn_b4,
                                                    float4* __restrict__ h1_4){
  int node = blockIdx.x*4 + (threadIdx.x >> 6);
  if (node >= NN) return;
  int lane = threadIdx.x & 63;
  int q = lane >> 4, f = lane & 15;
  int beg = off[node], end = off[node+1];
  float4 acc = {0.f,0.f,0.f,0.f};
  for (int c = beg; c < end; c += 64){
    int n = end - c; if (n > 64) n = 64;
    int idx = (lane < n) ? csr[c + lane] : 0;
    for (int k = 0; k < n; k += 16){
      int e0 = k + q, e1 = k + 4 + q, e2 = k + 8 + q, e3 = k + 12 + q;
      int s0 = __shfl(idx, e0, 64);
      int s1 = __shfl(idx, e1, 64);
      int s2 = __shfl(idx, e2, 64);
      int s3 = __shfl(idx, e3, 64);
      if (e0 < n) row_acc<M>(hs4, hsH, (size_t)s0, f, 1.f, acc);
      if (e1 < n) row_acc<M>(hs4, hsH, (size_t)s1, f, 1.f, acc);
      if (e2 < n) row_acc<M>(hs4, hsH, (size_t)s2, f, 1.f, acc);
      if (e3 < n) row_acc<M>(hs4, hsH, (size_t)s3, f, 1.f, acc);
    }
  }
  #pragma unroll
  for (int o = 16; o <= 32; o <<= 1){
    acc.x += __shfl_xor(acc.x, o, 64);
    acc.y += __shfl_xor(acc.y, o, 64);
    acc.z += __shfl_xor(acc.z, o, 64);
    acc.w += __shfl_xor(acc.w, o, 64);
  }
  if (q == 0){
    float4 s  = hs4[(size_t)node*16 + f];      // self term from f32
    float  di = dinv[node];
    float4 b4 = gcn_b4[f];
    float4 o;
    o.x = fmaxf((acc.x + s.x)*di + b4.x, 0.f);
    o.y = fmaxf((acc.y + s.y)*di + b4.y, 0.f);
    o.z = fmaxf((acc.z + s.z)*di + b4.z, 0.f);
    o.w = fmaxf((acc.w + s.w)*di + b4.w, 0.f);
    h1_4[(size_t)node*16 + f] = o;
  }
}

// GAT: single-pass softmax gather (shift-invariant; clamp guards overflow)
template<int M>
__global__ __launch_bounds__(256) void k_gat_gather(const int* __restrict__ csr,
                                                    const int* __restrict__ off,
                                                    const float* __restrict__ as_,
                                                    const float* __restrict__ ad_,
                                                    const float4* __restrict__ h2pre4,
                                                    const uint2*  __restrict__ h2preH,
                                                    const float4* __restrict__ gat_b4,
                                                    float4* __restrict__ h2_4,
                                                    uint2* __restrict__ h2H){
  int node = blockIdx.x*4 + (threadIdx.x >> 6);
  if (node >= NN) return;
  int lane = threadIdx.x & 63;
  int q = lane >> 4, f = lane & 15;
  int beg = off[node], end = off[node+1];
  float adi = ad_[node];
  float ps = expf(fminf(lrelu(as_[node] + adi), 80.f));
  float ssum = 0.f;
  float4 acc = {0.f,0.f,0.f,0.f};
  for (int c = beg; c < end; c += 64){
    int n = end - c; if (n > 64) n = 64;
    int idx = 0; float pv = 0.f;
    if (lane < n){
      idx = csr[c + lane];
      pv = expf(fminf(lrelu(as_[idx] + adi), 80.f));
    }
    for (int k = 0; k < n; k += 16){
      int e0 = k + q, e1 = k + 4 + q, e2 = k + 8 + q, e3 = k + 12 + q;
      int s0 = __shfl(idx, e0, 64); float p0 = __shfl(pv, e0, 64);
      int s1 = __shfl(idx, e1, 64); float p1 = __shfl(pv, e1, 64);
      int s2 = __shfl(idx, e2, 64); float p2 = __shfl(pv, e2, 64);
      int s3 = __shfl(idx, e3, 64); float p3 = __shfl(pv, e3, 64);
      if (e0 < n){ row_acc<M>(h2pre4, h2preH, (size_t)s0, f, p0, acc); ssum += p0; }
      if (e1 < n){ row_acc<M>(h2pre4, h2preH, (size_t)s1, f, p1, acc); ssum += p1; }
      if (e2 < n){ row_acc<M>(h2pre4, h2preH, (size_t)s2, f, p2, acc); ssum += p2; }
      if (e3 < n){ row_acc<M>(h2pre4, h2preH, (size_t)s3, f, p3, acc); ssum += p3; }
    }
  }
  #pragma unroll
  for (int o = 16; o <= 32; o <<= 1){
    acc.x += __shfl_xor(acc.x, o, 64);
    acc.y += __shfl_xor(acc.y, o, 64);
    acc.z += __shfl_xor(acc.z, o, 64);
    acc.w += __shfl_xor(acc.w, o, 64);
    ssum  += __shfl_xor(ssum,  o, 64);
  }
  if (q == 0){
    float inv = 1.f/(ssum + ps);
    float4 h0 = h2pre4[(size_t)node*16 + f];   // self term from f32
    float4 b4 = gat_b4[f];
    float4 o;
    o.x = fmaxf((acc.x + h0.x*ps)*inv + b4.x, 0.f);
    o.y = fmaxf((acc.y + h0.y*ps)*inv + b4.y, 0.f);
    o.z = fmaxf((acc.z + h0.z*ps)*inv + b4.z, 0.f);
    o.w = fmaxf((acc.w + h0.w*ps)*inv + b4.w, 0.f);
    h2_4[(size_t)node*16 + f] = o;
    if constexpr (M == 1){
      union { half2 h[2]; uint2 u; } pk;
      pk.h[0] = __floats2half2_rn(o.x, o.y);
      pk.h[1] = __floats2half2_rn(o.z, o.w);
      h2H[(size_t)node*16 + f] = pk.u;
    }
  }
}

// SAGE gather: mean of h2 rows
template<int M>
__global__ __launch_bounds__(256) void k_sage_gather(const int* __restrict__ csr,
                                                     const int* __restrict__ off,
                                                     const int* __restrict__ cnt,
                                                     const float4* __restrict__ h2_4,
                                                     const uint2*  __restrict__ h2H,
                                                     float4* __restrict__ mean4){
  int node = blockIdx.x*4 + (threadIdx.x >> 6);
  if (node >= NN) return;
  int lane = threadIdx.x & 63;
  int q = lane >> 4, f = lane & 15;
  int beg = off[node], end = off[node+1];
  float4 acc = {0.f,0.f,0.f,0.f};
  for (int c = beg; c < end; c += 64){
    int n = end - c; if (n > 64) n = 64;
    int idx = (lane < n) ? csr[c + lane] : 0;
    for (int k = 0; k < n; k += 16){
      int e0 = k + q, e1 = k + 4 + q, e2 = k + 8 + q, e3 = k + 12 + q;
      int s0 = __shfl(idx, e0, 64);
      int s1 = __shfl(idx, e1, 64);
      int s2 = __shfl(idx, e2, 64);
      int s3 = __shfl(idx, e3, 64);
      if (e0 < n) row_acc<M>(h2_4, h2H, (size_t)s0, f, 1.f, acc);
      if (e1 < n) row_acc<M>(h2_4, h2H, (size_t)s1, f, 1.f, acc);
      if (e2 < n) row_acc<M>(h2_4, h2H, (size_t)s2, f, 1.f, acc);
      if (e3 < n) row_acc<M>(h2_4, h2H, (size_t)s3, f, 1.f, acc);
    }
  }
  #pragma unroll
  for (int o = 16; o <= 32; o <<= 1){
    acc.x += __shfl_xor(acc.x, o, 64);
    acc.y += __shfl_xor(acc.y, o, 64);
    acc.z += __shfl_xor(acc.z, o, 64);
    acc.w += __shfl_xor(acc.w, o, 64);
  }
  if (q == 0){
    float inv = 1.f/fmaxf((float)cnt[node], 1.f);
    float4 o = {acc.x*inv, acc.y*inv, acc.z*inv, acc.w*inv};
    mean4[(size_t)node*16 + f] = o;
  }
}

// ---------------- launch ----------------

extern "C" void kernel_launch(void* const* d_in, const int* in_sizes, int n_in,
                              void* d_out, int out_size, void* d_ws, size_t ws_size,
                              hipStream_t stream) {
  const float* x      = (const float*)d_in[0];
  const int*   ei     = (const int*)d_in[1];
  const int*   src    = ei;
  const int*   dstp   = ei + NE;
  const float* gcn_w  = (const float*)d_in[2];
  const float* gcn_b  = (const float*)d_in[3];
  const float* gat_w  = (const float*)d_in[4];
  const float* att_s  = (const float*)d_in[5];
  const float* att_d  = (const float*)d_in[6];
  const float* gat_b  = (const float*)d_in[7];
  const float* s_wl   = (const float*)d_in[8];
  const float* s_wr   = (const float*)d_in[9];
  const float* s_b    = (const float*)d_in[10];
  float* outp = (float*)d_out;

  // workspace layout (4-byte words)
  int*   ghist = (int*)d_ws;             // 128 (98 used)
  int*   bases = ghist + 128;            // 128 (99 used)
  int*   cur   = bases + 128;            // 128 (98 used)
  int*   cnt   = cur + 128;              // NN
  int*   off   = cnt + NN;               // NN+1 (+pad to NN+8)
  float* dinv  = (float*)(off + NN + 8);
  float* as_   = dinv + NN;
  float* ad_   = as_  + NN;
  unsigned* bucketed = (unsigned*)(ad_ + NN);   // NE
  int*   csr   = (int*)(bucketed + NE);         // NE
  float* BIG0  = (float*)(csr + NE);            // N*HID f32
  float* BIG1  = BIG0 + (size_t)NN*HID;

  size_t base_words = 384 + (size_t)5*NN + 8 + (size_t)2*NE;
  size_t need2 = (base_words + (size_t)2*NN*HID)*4;   // + 2 big f32 ws buffers

  const size_t NH = (size_t)NN*HID;
  const int B = 256;
  const int GROWS = (NN + 31)/32;
  const int GG = (NN + 3)/4;
  const int GA = (NE + ACH - 1)/ACH;

  // CSR build: bucket sort (no global scatter atomics, single dst read per phase)
  k_zero_i <<<1, 128, 0, stream>>>(ghist, NBUK);
  kA0      <<<GA, B, 0, stream>>>(dstp, ghist);
  k_scan_bk<<<1, 128, 0, stream>>>(ghist, bases, cur, off);
  kA1      <<<GA, B, 0, stream>>>(src, dstp, cur, bucketed);
  kB       <<<NBUK, 512, 0, stream>>>(bucketed, bases, csr, off, cnt, dinv);

  if (ws_size >= need2){
    // fp16 tier: f32 ping-pong in ws; fp16 mirrors live in d_out
    float* P_hs    = BIG0;
    float* P_h1    = BIG1;
    float* P_h2pre = BIG0;                 // hs dead after gcn_gather
    float* P_h2    = BIG1;                 // h1 dead after gat_lin
    float* P_mean  = BIG0;                 // h2pre dead after gat_gather
    __half* HS_H    = (__half*)outp;       // NH halfs (first half of d_out)
    __half* H2PRE_H = (__half*)outp + NH;  // NH halfs (second half)
    __half* H2_H    = (__half*)outp;       // reuse hsH slot after gcn_gather

    // GCN
    k_gemm_in<1><<<GROWS, B, 0, stream>>>(x, gcn_w, dinv, P_hs, HS_H);
    k_gcn_gather<1><<<GG, B, 0, stream>>>(csr, off, (const float4*)P_hs,
        (const uint2*)HS_H, dinv, (const float4*)gcn_b, (float4*)P_h1);

    // GAT
    k_gat_lin<1><<<GROWS, B, 0, stream>>>(P_h1, gat_w, att_s, att_d,
        P_h2pre, H2PRE_H, as_, ad_);
    k_gat_gather<1><<<GG, B, 0, stream>>>(csr, off, as_, ad_,
        (const float4*)P_h2pre, (const uint2*)H2PRE_H, (const float4*)gat_b,
        (float4*)P_h2, (uint2*)H2_H);

    // SAGE
    k_sage_gather<1><<<GG, B, 0, stream>>>(csr, off, cnt,
        (const float4*)P_h2, (const uint2*)H2_H, (float4*)P_mean);
    k_sage_dense<<<GROWS, B, 0, stream>>>(P_mean, P_h2, s_wl, s_wr, s_b, outp);
  } else {
    // f32 fallback: d_out time-shared as a big buffer
    float* P_hs    = outp;
    float* P_h1    = BIG0;
    float* P_h2pre = outp;
    float* P_h2    = BIG0;
    float* P_mean  = outp;

    k_gemm_in<0><<<GROWS, B, 0, stream>>>(x, gcn_w, dinv, P_hs, nullptr);
    k_gcn_gather<0><<<GG, B, 0, stream>>>(csr, off, (const float4*)P_hs,
        nullptr, dinv, (const float4*)gcn_b, (float4*)P_h1);
    k_gat_lin<0><<<GROWS, B, 0, stream>>>(P_h1, gat_w, att_s, att_d,
        P_h2pre, nullptr, as_, ad_);
    k_gat_gather<0><<<GG, B, 0, stream>>>(csr, off, as_, ad_,
        (const float4*)P_h2pre, nullptr, (const float4*)gat_b, (float4*)P_h2, nullptr);
    k_sage_gather<0><<<GG, B, 0, stream>>>(csr, off, cnt,
        (const float4*)P_h2, nullptr, (float4*)P_mean);
    k_sage_dense<<<GROWS, B, 0, stream>>>(P_mean, P_h2, s_wl, s_wr, s_b, outp);
  }
}

// Round 11
// 302.360 us; speedup vs baseline: 3.7170x; 1.0598x over previous
//
#include <hip/hip_runtime.h>
#include <hip/hip_fp16.h>
#include <math.h>

#define NN 100000
#define NE 1600000
#define INF_ 128
#define HID 64
#define NEG 0.2f
#define NBUK 196     // buckets of 512 dst nodes (196*512 = 100352 >= NN)
#define ACH 2048     // edges per block in bucket-build phases

__device__ __forceinline__ float lrelu(float v){ return v > 0.f ? v : NEG*v; }

// ---------------- CSR build: two-level LDS bucket sort (512-node buckets) -----

__global__ void k_zero_i(int* p, int n){
  int i = blockIdx.x*blockDim.x + threadIdx.x;
  if (i < n) p[i] = 0;
}

// A0: global bucket histogram (LDS-combined)
__global__ __launch_bounds__(256) void kA0(const int* __restrict__ dst,
                                           int* __restrict__ ghist){
  __shared__ int hist[NBUK];
  int t = threadIdx.x;
  if (t < NBUK) hist[t] = 0;
  __syncthreads();
  int eb = blockIdx.x*ACH;
  for (int i = t; i < ACH; i += 256){
    int e = eb + i;
    if (e < NE) atomicAdd(&hist[dst[e] >> 9], 1);
  }
  __syncthreads();
  if (t < NBUK && hist[t]) atomicAdd(&ghist[t], hist[t]);
}

// scan buckets -> bases (exclusive) + cursor init; sentinels
__global__ __launch_bounds__(256) void k_scan_bk(const int* __restrict__ ghist,
                                                 int* __restrict__ bases,
                                                 int* __restrict__ cur,
                                                 int* __restrict__ off){
  __shared__ int l[256];
  int t = threadIdx.x;
  int v = (t < NBUK) ? ghist[t] : 0;
  l[t] = v; __syncthreads();
  for (int o = 1; o < 256; o <<= 1){
    int u = (t >= o) ? l[t-o] : 0;
    __syncthreads();
    l[t] += u;
    __syncthreads();
  }
  if (t < NBUK){ bases[t] = l[t] - v; cur[t] = l[t] - v; }
  if (t == 0){ bases[NBUK] = NE; off[NN] = NE; }
}

// A1: partition edges into bucket-contiguous packed words (src<<9)|(d&511).
// Per-block chunk reservation -> block-exclusive write regions.
__global__ __launch_bounds__(256) void kA1(const int* __restrict__ src,
                                           const int* __restrict__ dst,
                                           int* cur,
                                           unsigned* __restrict__ bucketed){
  __shared__ unsigned pk[ACH];
  __shared__ unsigned char bk[ACH];
  __shared__ int hist[NBUK], base[NBUK];
  int t = threadIdx.x;
  if (t < NBUK) hist[t] = 0;
  __syncthreads();
  int eb = blockIdx.x*ACH;
  for (int i = t; i < ACH; i += 256){
    int e = eb + i;
    if (e < NE){
      int d = dst[e];
      int b = d >> 9;
      atomicAdd(&hist[b], 1);
      pk[i] = ((unsigned)src[e] << 9) | (unsigned)(d & 511);
      bk[i] = (unsigned char)b;
    } else bk[i] = 0xFF;
  }
  __syncthreads();
  if (t < NBUK){
    base[t] = hist[t] ? atomicAdd(&cur[t], hist[t]) : 0;
    hist[t] = 0;                      // reuse as local cursor
  }
  __syncthreads();
  for (int i = t; i < ACH; i += 256){
    if (bk[i] != 0xFF){
      int b = bk[i];
      int slot = atomicAdd(&hist[b], 1);
      bucketed[base[b] + slot] = pk[i];
    }
  }
}

// B: per-bucket CSR finalize (256 threads, 512 nodes/bucket).
__global__ __launch_bounds__(256) void kB(const unsigned* __restrict__ bucketed,
                                          const int* __restrict__ bases,
                                          int* __restrict__ csr,
                                          int* __restrict__ off,
                                          int* __restrict__ cnt,
                                          float* __restrict__ dinv){
  __shared__ int lc[512];
  __shared__ int lcur[512];
  __shared__ int red[256];
  int b = blockIdx.x, t = threadIdx.x;
  int bbase = bases[b], bend = bases[b+1];
  lc[t] = 0; lc[t + 256] = 0;
  __syncthreads();
  for (int e = bbase + t; e < bend; e += 256)
    atomicAdd(&lc[bucketed[e] & 511], 1);
  __syncthreads();
  int a0 = lc[2*t], a1 = lc[2*t+1];
  int s = a0 + a1;
  red[t] = s;
  __syncthreads();
  for (int o = 1; o < 256; o <<= 1){
    int v = (t >= o) ? red[t-o] : 0;
    __syncthreads();
    red[t] += v;
    __syncthreads();
  }
  int e0 = red[t] - s;
  lcur[2*t]   = e0;
  lcur[2*t+1] = e0 + a0;
  int node = b*512 + 2*t;
  if (node < NN){
    off[node]  = bbase + e0;
    cnt[node]  = a0;
    dinv[node] = rsqrtf((float)a0 + 1.f);
  }
  if (node + 1 < NN){
    off[node+1]  = bbase + e0 + a0;
    cnt[node+1]  = a1;
    dinv[node+1] = rsqrtf((float)a1 + 1.f);
  }
  __syncthreads();
  for (int e = bbase + t; e < bend; e += 256){
    unsigned w = bucketed[e];
    int slot = atomicAdd(&lcur[w & 511], 1);
    csr[bbase + slot] = (int)(w >> 9);
  }
}

// ---------------- dense linears: 8 rows/wave, 16-reg weight chunks ----------------

template<int M>
__global__ __launch_bounds__(256, 4) void k_gemm_in(const float* __restrict__ x,
                                                    const float* __restrict__ w,
                                                    const float* __restrict__ dinv,
                                                    float* __restrict__ hs,
                                                    __half* __restrict__ hsH){
  __shared__ float xl[4][8][INF_];
  const int wave = threadIdx.x >> 6, lane = threadIdx.x & 63;
  int rb = blockIdx.x*32 + wave*8;
  if (rb >= NN) return;
  #pragma unroll
  for (int r = 0; r < 8; ++r){
    xl[wave][r][lane]      = x[(size_t)(rb+r)*INF_ + lane];
    xl[wave][r][lane + 64] = x[(size_t)(rb+r)*INF_ + lane + 64];
  }
  float acc[8] = {0.f,0.f,0.f,0.f,0.f,0.f,0.f,0.f};
  #pragma unroll
  for (int c = 0; c < 8; ++c){
    float wv[16];
    #pragma unroll
    for (int j = 0; j < 16; ++j) wv[j] = w[(c*16 + j)*HID + lane];
    #pragma unroll
    for (int r = 0; r < 8; ++r)
      #pragma unroll
      for (int j = 0; j < 16; ++j)
        acc[r] = fmaf(xl[wave][r][c*16 + j], wv[j], acc[r]);
  }
  #pragma unroll
  for (int r = 0; r < 8; ++r){
    float v = acc[r]*dinv[rb+r];
    hs[(size_t)(rb+r)*HID + lane] = v;
    if constexpr (M == 1) hsH[(size_t)(rb+r)*HID + lane] = __float2half(v);
  }
}

template<int M>
__global__ __launch_bounds__(256, 4) void k_gat_lin(const float* __restrict__ h1,
                                                    const float* __restrict__ w,
                                                    const float* __restrict__ atts,
                                                    const float* __restrict__ attd,
                                                    float* __restrict__ h2pre,
                                                    __half* __restrict__ h2preH,
                                                    float* __restrict__ as_,
                                                    float* __restrict__ ad_){
  __shared__ float xl[4][8][HID];
  __shared__ float asl[HID], adl[HID];
  if (threadIdx.x < HID){
    asl[threadIdx.x] = atts[threadIdx.x];
    adl[threadIdx.x] = attd[threadIdx.x];
  }
  __syncthreads();
  const int wave = threadIdx.x >> 6, lane = threadIdx.x & 63;
  int rb = blockIdx.x*32 + wave*8;
  if (rb >= NN) return;
  #pragma unroll
  for (int r = 0; r < 8; ++r)
    xl[wave][r][lane] = h1[(size_t)(rb+r)*HID + lane];
  float acc[8] = {0.f,0.f,0.f,0.f,0.f,0.f,0.f,0.f};
  #pragma unroll
  for (int c = 0; c < 4; ++c){
    float wv[16];
    #pragma unroll
    for (int j = 0; j < 16; ++j) wv[j] = w[(c*16 + j)*HID + lane];
    #pragma unroll
    for (int r = 0; r < 8; ++r)
      #pragma unroll
      for (int j = 0; j < 16; ++j)
        acc[r] = fmaf(xl[wave][r][c*16 + j], wv[j], acc[r]);
  }
  #pragma unroll
  for (int r = 0; r < 8; ++r){
    h2pre[(size_t)(rb+r)*HID + lane] = acc[r];
    if constexpr (M == 1) h2preH[(size_t)(rb+r)*HID + lane] = __float2half(acc[r]);
    xl[wave][r][lane] = acc[r];
  }
  int rr = lane >> 3, t = lane & 7;
  float vs = 0.f, vd = 0.f;
  #pragma unroll
  for (int i = 0; i < 8; ++i){
    float v = xl[wave][rr][t + 8*i];
    vs = fmaf(v, asl[t + 8*i], vs);
    vd = fmaf(v, adl[t + 8*i], vd);
  }
  #pragma unroll
  for (int o = 1; o < 8; o <<= 1){
    vs += __shfl_xor(vs, o, 64);
    vd += __shfl_xor(vd, o, 64);
  }
  if (t == 0){ as_[rb + rr] = vs; ad_[rb + rr] = vd; }
}

__global__ __launch_bounds__(256, 4) void k_sage_dense(const float* mean,
                                                       const float* __restrict__ h2,
                                                       const float* __restrict__ wlh,
                                                       const float* __restrict__ wrh,
                                                       const float* __restrict__ b,
                                                       float* out){
  __shared__ float ml[4][8][HID];
  __shared__ float hl[4][8][HID];
  const int wave = threadIdx.x >> 6, lane = threadIdx.x & 63;
  int rb = blockIdx.x*32 + wave*8;
  if (rb >= NN) return;
  float bl = b[lane];
  #pragma unroll
  for (int r = 0; r < 8; ++r){
    ml[wave][r][lane] = mean[(size_t)(rb+r)*HID + lane];
    hl[wave][r][lane] = h2[(size_t)(rb+r)*HID + lane];
  }
  float acc[8] = {bl,bl,bl,bl,bl,bl,bl,bl};
  #pragma unroll
  for (int c = 0; c < 4; ++c){
    float wvl[16], wvr[16];
    #pragma unroll
    for (int j = 0; j < 16; ++j){
      wvl[j] = wlh[(c*16 + j)*HID + lane];
      wvr[j] = wrh[(c*16 + j)*HID + lane];
    }
    #pragma unroll
    for (int r = 0; r < 8; ++r)
      #pragma unroll
      for (int j = 0; j < 16; ++j){
        acc[r] = fmaf(ml[wave][r][c*16 + j], wvl[j], acc[r]);
        acc[r] = fmaf(hl[wave][r][c*16 + j], wvr[j], acc[r]);
      }
  }
  #pragma unroll
  for (int r = 0; r < 8; ++r)
    out[(size_t)(rb+r)*HID + lane] = acc[r];
}

// ---------------- gathers: DUAL-NODE per wave, 4-row-slot, fp16 rows (M=1) ----
// off[] = segment starts (NN+1). NN = 12500*8 exactly -> no node guards.

template<int M>
__device__ __forceinline__ void row_acc(const float4* __restrict__ r4,
                                        const uint2*  __restrict__ rh,
                                        size_t s, int f, float p, float4& acc){
  if constexpr (M == 1){
    uint2 v = rh[s*16 + f];
    half2* ph = (half2*)&v;
    float2 fa = __half22float2(ph[0]);
    float2 fb = __half22float2(ph[1]);
    acc.x = fmaf(fa.x, p, acc.x); acc.y = fmaf(fa.y, p, acc.y);
    acc.z = fmaf(fb.x, p, acc.z); acc.w = fmaf(fb.y, p, acc.w);
  } else {
    float4 r = r4[s*16 + f];
    acc.x = fmaf(r.x, p, acc.x); acc.y = fmaf(r.y, p, acc.y);
    acc.z = fmaf(r.z, p, acc.z); acc.w = fmaf(r.w, p, acc.w);
  }
}

// GCN dual-node gather
template<int M>
__global__ __launch_bounds__(256) void k_gcn_gather(const int* __restrict__ csr,
                                                    const int* __restrict__ off,
                                                    const float4* __restrict__ hs4,
                                                    const uint2*  __restrict__ hsH,
                                                    const float* __restrict__ dinv,
                                                    const float4* __restrict__ gcn_b4,
                                                    float4* __restrict__ h1_4){
  const int wave = threadIdx.x >> 6, lane = threadIdx.x & 63;
  int n0 = blockIdx.x*8 + wave*2, n1 = n0 + 1;
  int q = lane >> 4, f = lane & 15;
  int b0 = off[n0], e0_ = off[n0+1];
  int b1 = e0_,     e1_ = off[n0+2];
  float4 A0 = {0,0,0,0}, A1 = {0,0,0,0};
  int c0 = b0, c1 = b1;
  while (c0 < e0_ || c1 < e1_){
    int m0 = e0_ - c0; if (m0 > 64) m0 = 64;
    int m1 = e1_ - c1; if (m1 > 64) m1 = 64;
    int i0 = (lane < m0) ? csr[c0 + lane] : 0;
    int i1 = (lane < m1) ? csr[c1 + lane] : 0;
    int mm = m0 > m1 ? m0 : m1;
    for (int k = 0; k < mm; k += 16){
      int ka = k + q, kb = k + 4 + q, kc = k + 8 + q, kd = k + 12 + q;
      int s0a = __shfl(i0, ka, 64), s1a = __shfl(i1, ka, 64);
      int s0b = __shfl(i0, kb, 64), s1b = __shfl(i1, kb, 64);
      int s0c = __shfl(i0, kc, 64), s1c = __shfl(i1, kc, 64);
      int s0d = __shfl(i0, kd, 64), s1d = __shfl(i1, kd, 64);
      if (ka < m0) row_acc<M>(hs4, hsH, (size_t)s0a, f, 1.f, A0);
      if (ka < m1) row_acc<M>(hs4, hsH, (size_t)s1a, f, 1.f, A1);
      if (kb < m0) row_acc<M>(hs4, hsH, (size_t)s0b, f, 1.f, A0);
      if (kb < m1) row_acc<M>(hs4, hsH, (size_t)s1b, f, 1.f, A1);
      if (kc < m0) row_acc<M>(hs4, hsH, (size_t)s0c, f, 1.f, A0);
      if (kc < m1) row_acc<M>(hs4, hsH, (size_t)s1c, f, 1.f, A1);
      if (kd < m0) row_acc<M>(hs4, hsH, (size_t)s0d, f, 1.f, A0);
      if (kd < m1) row_acc<M>(hs4, hsH, (size_t)s1d, f, 1.f, A1);
    }
    c0 += 64; c1 += 64;
  }
  #pragma unroll
  for (int o = 16; o <= 32; o <<= 1){
    A0.x += __shfl_xor(A0.x, o, 64); A1.x += __shfl_xor(A1.x, o, 64);
    A0.y += __shfl_xor(A0.y, o, 64); A1.y += __shfl_xor(A1.y, o, 64);
    A0.z += __shfl_xor(A0.z, o, 64); A1.z += __shfl_xor(A1.z, o, 64);
    A0.w += __shfl_xor(A0.w, o, 64); A1.w += __shfl_xor(A1.w, o, 64);
  }
  if (q < 2){
    int node = q ? n1 : n0;
    float4 A = q ? A1 : A0;
    float4 s  = hs4[(size_t)node*16 + f];
    float  di = dinv[node];
    float4 b4 = gcn_b4[f];
    float4 o;
    o.x = fmaxf((A.x + s.x)*di + b4.x, 0.f);
    o.y = fmaxf((A.y + s.y)*di + b4.y, 0.f);
    o.z = fmaxf((A.z + s.z)*di + b4.z, 0.f);
    o.w = fmaxf((A.w + s.w)*di + b4.w, 0.f);
    h1_4[(size_t)node*16 + f] = o;
  }
}

// GAT dual-node single-pass softmax gather
template<int M>
__global__ __launch_bounds__(256) void k_gat_gather(const int* __restrict__ csr,
                                                    const int* __restrict__ off,
                                                    const float* __restrict__ as_,
                                                    const float* __restrict__ ad_,
                                                    const float4* __restrict__ h2pre4,
                                                    const uint2*  __restrict__ h2preH,
                                                    const float4* __restrict__ gat_b4,
                                                    float4* __restrict__ h2_4,
                                                    uint2* __restrict__ h2H){
  const int wave = threadIdx.x >> 6, lane = threadIdx.x & 63;
  int n0 = blockIdx.x*8 + wave*2, n1 = n0 + 1;
  int q = lane >> 4, f = lane & 15;
  int b0 = off[n0], e0_ = off[n0+1];
  int b1 = e0_,     e1_ = off[n0+2];
  float adi0 = ad_[n0], adi1 = ad_[n1];
  float ps0 = expf(fminf(lrelu(as_[n0] + adi0), 80.f));
  float ps1 = expf(fminf(lrelu(as_[n1] + adi1), 80.f));
  float S0 = 0.f, S1 = 0.f;
  float4 A0 = {0,0,0,0}, A1 = {0,0,0,0};
  int c0 = b0, c1 = b1;
  while (c0 < e0_ || c1 < e1_){
    int m0 = e0_ - c0; if (m0 > 64) m0 = 64;
    int m1 = e1_ - c1; if (m1 > 64) m1 = 64;
    int i0 = 0, i1 = 0; float p0 = 0.f, p1 = 0.f;
    if (lane < m0){ i0 = csr[c0 + lane]; p0 = expf(fminf(lrelu(as_[i0] + adi0), 80.f)); }
    if (lane < m1){ i1 = csr[c1 + lane]; p1 = expf(fminf(lrelu(as_[i1] + adi1), 80.f)); }
    int mm = m0 > m1 ? m0 : m1;
    for (int k = 0; k < mm; k += 16){
      int ka = k + q, kb = k + 4 + q, kc = k + 8 + q, kd = k + 12 + q;
      int s0a = __shfl(i0, ka, 64); float w0a = __shfl(p0, ka, 64);
      int s1a = __shfl(i1, ka, 64); float w1a = __shfl(p1, ka, 64);
      int s0b = __shfl(i0, kb, 64); float w0b = __shfl(p0, kb, 64);
      int s1b = __shfl(i1, kb, 64); float w1b = __shfl(p1, kb, 64);
      int s0c = __shfl(i0, kc, 64); float w0c = __shfl(p0, kc, 64);
      int s1c = __shfl(i1, kc, 64); float w1c = __shfl(p1, kc, 64);
      int s0d = __shfl(i0, kd, 64); float w0d = __shfl(p0, kd, 64);
      int s1d = __shfl(i1, kd, 64); float w1d = __shfl(p1, kd, 64);
      if (ka < m0){ row_acc<M>(h2pre4, h2preH, (size_t)s0a, f, w0a, A0); S0 += w0a; }
      if (ka < m1){ row_acc<M>(h2pre4, h2preH, (size_t)s1a, f, w1a, A1); S1 += w1a; }
      if (kb < m0){ row_acc<M>(h2pre4, h2preH, (size_t)s0b, f, w0b, A0); S0 += w0b; }
      if (kb < m1){ row_acc<M>(h2pre4, h2preH, (size_t)s1b, f, w1b, A1); S1 += w1b; }
      if (kc < m0){ row_acc<M>(h2pre4, h2preH, (size_t)s0c, f, w0c, A0); S0 += w0c; }
      if (kc < m1){ row_acc<M>(h2pre4, h2preH, (size_t)s1c, f, w1c, A1); S1 += w1c; }
      if (kd < m0){ row_acc<M>(h2pre4, h2preH, (size_t)s0d, f, w0d, A0); S0 += w0d; }
      if (kd < m1){ row_acc<M>(h2pre4, h2preH, (size_t)s1d, f, w1d, A1); S1 += w1d; }
    }
    c0 += 64; c1 += 64;
  }
  #pragma unroll
  for (int o = 16; o <= 32; o <<= 1){
    A0.x += __shfl_xor(A0.x, o, 64); A1.x += __shfl_xor(A1.x, o, 64);
    A0.y += __shfl_xor(A0.y, o, 64); A1.y += __shfl_xor(A1.y, o, 64);
    A0.z += __shfl_xor(A0.z, o, 64); A1.z += __shfl_xor(A1.z, o, 64);
    A0.w += __shfl_xor(A0.w, o, 64); A1.w += __shfl_xor(A1.w, o, 64);
    S0   += __shfl_xor(S0,   o, 64); S1   += __shfl_xor(S1,   o, 64);
  }
  if (q < 2){
    int node = q ? n1 : n0;
    float4 A = q ? A1 : A0;
    float ps = q ? ps1 : ps0;
    float inv = 1.f/((q ? S1 : S0) + ps);
    float4 h0 = h2pre4[(size_t)node*16 + f];
    float4 b4 = gat_b4[f];
    float4 o;
    o.x = fmaxf((A.x + h0.x*ps)*inv + b4.x, 0.f);
    o.y = fmaxf((A.y + h0.y*ps)*inv + b4.y, 0.f);
    o.z = fmaxf((A.z + h0.z*ps)*inv + b4.z, 0.f);
    o.w = fmaxf((A.w + h0.w*ps)*inv + b4.w, 0.f);
    h2_4[(size_t)node*16 + f] = o;
    if constexpr (M == 1){
      union { half2 h[2]; uint2 u; } pk;
      pk.h[0] = __floats2half2_rn(o.x, o.y);
      pk.h[1] = __floats2half2_rn(o.z, o.w);
      h2H[(size_t)node*16 + f] = pk.u;
    }
  }
}

// SAGE dual-node mean gather
template<int M>
__global__ __launch_bounds__(256) void k_sage_gather(const int* __restrict__ csr,
                                                     const int* __restrict__ off,
                                                     const int* __restrict__ cnt,
                                                     const float4* __restrict__ h2_4,
                                                     const uint2*  __restrict__ h2H,
                                                     float4* __restrict__ mean4){
  const int wave = threadIdx.x >> 6, lane = threadIdx.x & 63;
  int n0 = blockIdx.x*8 + wave*2, n1 = n0 + 1;
  int q = lane >> 4, f = lane & 15;
  int b0 = off[n0], e0_ = off[n0+1];
  int b1 = e0_,     e1_ = off[n0+2];
  float4 A0 = {0,0,0,0}, A1 = {0,0,0,0};
  int c0 = b0, c1 = b1;
  while (c0 < e0_ || c1 < e1_){
    int m0 = e0_ - c0; if (m0 > 64) m0 = 64;
    int m1 = e1_ - c1; if (m1 > 64) m1 = 64;
    int i0 = (lane < m0) ? csr[c0 + lane] : 0;
    int i1 = (lane < m1) ? csr[c1 + lane] : 0;
    int mm = m0 > m1 ? m0 : m1;
    for (int k = 0; k < mm; k += 16){
      int ka = k + q, kb = k + 4 + q, kc = k + 8 + q, kd = k + 12 + q;
      int s0a = __shfl(i0, ka, 64), s1a = __shfl(i1, ka, 64);
      int s0b = __shfl(i0, kb, 64), s1b = __shfl(i1, kb, 64);
      int s0c = __shfl(i0, kc, 64), s1c = __shfl(i1, kc, 64);
      int s0d = __shfl(i0, kd, 64), s1d = __shfl(i1, kd, 64);
      if (ka < m0) row_acc<M>(h2_4, h2H, (size_t)s0a, f, 1.f, A0);
      if (ka < m1) row_acc<M>(h2_4, h2H, (size_t)s1a, f, 1.f, A1);
      if (kb < m0) row_acc<M>(h2_4, h2H, (size_t)s0b, f, 1.f, A0);
      if (kb < m1) row_acc<M>(h2_4, h2H, (size_t)s1b, f, 1.f, A1);
      if (kc < m0) row_acc<M>(h2_4, h2H, (size_t)s0c, f, 1.f, A0);
      if (kc < m1) row_acc<M>(h2_4, h2H, (size_t)s1c, f, 1.f, A1);
      if (kd < m0) row_acc<M>(h2_4, h2H, (size_t)s0d, f, 1.f, A0);
      if (kd < m1) row_acc<M>(h2_4, h2H, (size_t)s1d, f, 1.f, A1);
    }
    c0 += 64; c1 += 64;
  }
  #pragma unroll
  for (int o = 16; o <= 32; o <<= 1){
    A0.x += __shfl_xor(A0.x, o, 64); A1.x += __shfl_xor(A1.x, o, 64);
    A0.y += __shfl_xor(A0.y, o, 64); A1.y += __shfl_xor(A1.y, o, 64);
    A0.z += __shfl_xor(A0.z, o, 64); A1.z += __shfl_xor(A1.z, o, 64);
    A0.w += __shfl_xor(A0.w, o, 64); A1.w += __shfl_xor(A1.w, o, 64);
  }
  if (q < 2){
    int node = q ? n1 : n0;
    float4 A = q ? A1 : A0;
    float inv = 1.f/fmaxf((float)cnt[node], 1.f);
    float4 o = {A.x*inv, A.y*inv, A.z*inv, A.w*inv};
    mean4[(size_t)node*16 + f] = o;
  }
}

// ---------------- launch ----------------

extern "C" void kernel_launch(void* const* d_in, const int* in_sizes, int n_in,
                              void* d_out, int out_size, void* d_ws, size_t ws_size,
                              hipStream_t stream) {
  const float* x      = (const float*)d_in[0];
  const int*   ei     = (const int*)d_in[1];
  const int*   src    = ei;
  const int*   dstp   = ei + NE;
  const float* gcn_w  = (const float*)d_in[2];
  const float* gcn_b  = (const float*)d_in[3];
  const float* gat_w  = (const float*)d_in[4];
  const float* att_s  = (const float*)d_in[5];
  const float* att_d  = (const float*)d_in[6];
  const float* gat_b  = (const float*)d_in[7];
  const float* s_wl   = (const float*)d_in[8];
  const float* s_wr   = (const float*)d_in[9];
  const float* s_b    = (const float*)d_in[10];
  float* outp = (float*)d_out;

  // workspace layout (4-byte words)
  int*   ghist = (int*)d_ws;             // 256 (196 used)
  int*   bases = ghist + 256;            // 256 (197 used)
  int*   cur   = bases + 256;            // 256 (196 used)
  int*   cnt   = cur + 256;              // NN
  int*   off   = cnt + NN;               // NN+1 (+pad)
  float* dinv  = (float*)(off + NN + 8);
  float* as_   = dinv + NN;
  float* ad_   = as_  + NN;
  unsigned* bucketed = (unsigned*)(ad_ + NN);   // NE
  int*   csr   = (int*)(bucketed + NE);         // NE
  float* BIG0  = (float*)(csr + NE);            // N*HID f32
  float* BIG1  = BIG0 + (size_t)NN*HID;

  size_t base_words = 768 + (size_t)5*NN + 8 + (size_t)2*NE;
  size_t need2 = (base_words + (size_t)2*NN*HID)*4;

  const size_t NH = (size_t)NN*HID;
  const int B = 256;
  const int GROWS = (NN + 31)/32;
  const int GG2 = NN/8;                 // dual-node gathers: 12500 blocks exact
  const int GA = (NE + ACH - 1)/ACH;

  // CSR build: bucket sort
  k_zero_i <<<1, 256, 0, stream>>>(ghist, NBUK);
  kA0      <<<GA, B, 0, stream>>>(dstp, ghist);
  k_scan_bk<<<1, 256, 0, stream>>>(ghist, bases, cur, off);
  kA1      <<<GA, B, 0, stream>>>(src, dstp, cur, bucketed);
  kB       <<<NBUK, 256, 0, stream>>>(bucketed, bases, csr, off, cnt, dinv);

  if (ws_size >= need2){
    float* P_hs    = BIG0;
    float* P_h1    = BIG1;
    float* P_h2pre = BIG0;
    float* P_h2    = BIG1;
    float* P_mean  = BIG0;
    __half* HS_H    = (__half*)outp;
    __half* H2PRE_H = (__half*)outp + NH;
    __half* H2_H    = (__half*)outp;

    k_gemm_in<1><<<GROWS, B, 0, stream>>>(x, gcn_w, dinv, P_hs, HS_H);
    k_gcn_gather<1><<<GG2, B, 0, stream>>>(csr, off, (const float4*)P_hs,
        (const uint2*)HS_H, dinv, (const float4*)gcn_b, (float4*)P_h1);

    k_gat_lin<1><<<GROWS, B, 0, stream>>>(P_h1, gat_w, att_s, att_d,
        P_h2pre, H2PRE_H, as_, ad_);
    k_gat_gather<1><<<GG2, B, 0, stream>>>(csr, off, as_, ad_,
        (const float4*)P_h2pre, (const uint2*)H2PRE_H, (const float4*)gat_b,
        (float4*)P_h2, (uint2*)H2_H);

    k_sage_gather<1><<<GG2, B, 0, stream>>>(csr, off, cnt,
        (const float4*)P_h2, (const uint2*)H2_H, (float4*)P_mean);
    k_sage_dense<<<GROWS, B, 0, stream>>>(P_mean, P_h2, s_wl, s_wr, s_b, outp);
  } else {
    float* P_hs    = outp;
    float* P_h1    = BIG0;
    float* P_h2pre = outp;
    float* P_h2    = BIG0;
    float* P_mean  = outp;

    k_gemm_in<0><<<GROWS, B, 0, stream>>>(x, gcn_w, dinv, P_hs, nullptr);
    k_gcn_gather<0><<<GG2, B, 0, stream>>>(csr, off, (const float4*)P_hs,
        nullptr, dinv, (const float4*)gcn_b, (float4*)P_h1);
    k_gat_lin<0><<<GROWS, B, 0, stream>>>(P_h1, gat_w, att_s, att_d,
        P_h2pre, nullptr, as_, ad_);
    k_gat_gather<0><<<GG2, B, 0, stream>>>(csr, off, as_, ad_,
        (const float4*)P_h2pre, nullptr, (const float4*)gat_b, (float4*)P_h2, nullptr);
    k_sage_gather<0><<<GG2, B, 0, stream>>>(csr, off, cnt,
        (const float4*)P_h2, nullptr, (float4*)P_mean);
    k_sage_dense<<<GROWS, B, 0, stream>>>(P_mean, P_h2, s_wl, s_wr, s_b, outp);
  }
}